// Round 1
// baseline (2793.659 us; speedup 1.0000x reference)
//
#include <hip/hip_runtime.h>

// ---------------------------------------------------------------------------
// MultiTaskModel: 5x stride-2 conv backbone (fp32) -> pool/FC/argmax ->
// per-sample expert UNet decoder (5x fused up2+conv3x3 + 1x1 head).
// Round 0: correct all-fp32 baseline with LDS-tiled direct convs.
// ---------------------------------------------------------------------------

// MODE 0: stride-2 downsample conv, SAME (pad bottom/right only): ih = 2*oh+kh
// MODE 1: fused nearest 2x upsample + conv3x3 SAME (pad 1):       ih = (oh+kh-1)>>1
template<int CIN,int COUT,int HO,int WO,int TH,int TW,int CO_BLK,int ACC,int CK,int MODE>
__global__ __launch_bounds__(256)
void conv3x3_kernel(const float* __restrict__ in, const float* __restrict__ W,
                    const float* __restrict__ Bias, float* __restrict__ out,
                    const int* __restrict__ cls, int wstride, int bstride)
{
    constexpr int HI = (MODE==0) ? HO*2 : HO/2;
    constexpr int WI = (MODE==0) ? WO*2 : WO/2;
    constexpr int R  = (MODE==0) ? 2*TH+1 : TH/2+2;
    constexpr int C  = (MODE==0) ? 2*TW+1 : TW/2+2;
    constexpr int SP = TH*TW;            // spatial positions per block
    constexpr int NGRP = CO_BLK/ACC;     // co groups per block
    constexpr int GRP4 = ACC/4;          // float4 weight reads per k
    static_assert(SP*NGRP == 256, "block must be 256 threads");

    __shared__ __align__(16) float ilds[CK*R*C];
    __shared__ __align__(16) float wlds[CK*9*CO_BLK];

    const int n   = blockIdx.z;
    const int co0 = blockIdx.y * CO_BLK;
    constexpr int TILES_X = WO/TW;
    const int ty = blockIdx.x / TILES_X, tx = blockIdx.x % TILES_X;
    const int oh0 = ty*TH, ow0 = tx*TW;

    const int t   = threadIdx.x;
    const int p   = t % SP;      // spatial index in tile
    const int grp = t / SP;      // co group index
    const int py  = p / TW, px = p % TW;

    const float* Wb = W;
    const float* Bb = Bias;
    if (MODE==1) { int e = cls[n]; Wb += (long)e*wstride; Bb += (long)e*bstride; }
    (void)cls;

    float acc[ACC];
    #pragma unroll
    for (int i=0;i<ACC;i++) acc[i] = 0.f;

    const int r0 = (MODE==0) ? 2*oh0 : (oh0/2 - 1);
    const int c0 = (MODE==0) ? 2*ow0 : (ow0/2 - 1);

    for (int ci0 = 0; ci0 < CIN; ci0 += CK) {
        // ---- stage input tile (zero-padded) ----
        const float* ibase = in + ((long)n*CIN + ci0)*HI*WI;
        for (int idx = t; idx < CK*R*C; idx += 256) {
            int ck = idx/(R*C); int rc = idx%(R*C);
            int r = rc/C, c = rc%C;
            int ih = r0 + r, iw = c0 + c;
            float v = 0.f;
            if (ih >= 0 && ih < HI && iw >= 0 && iw < WI)
                v = ibase[(long)ck*HI*WI + ih*WI + iw];
            ilds[idx] = v;
        }
        // ---- stage weights: wlds[(ck*9+k)*CO_BLK + co] ----
        for (int idx = t; idx < CO_BLK*CK*9; idx += 256) {
            int co = idx % CO_BLK; int rem = idx / CO_BLK;   // rem = ck*9+k
            wlds[rem*CO_BLK + co] = Wb[(long)(co0+co)*CIN*9 + ci0*9 + rem];
        }
        __syncthreads();

        #pragma unroll
        for (int ck = 0; ck < CK; ++ck) {
            float xv[9];
            #pragma unroll
            for (int kh = 0; kh < 3; ++kh)
                #pragma unroll
                for (int kw = 0; kw < 3; ++kw) {
                    int tr, tc;
                    if (MODE==0) { tr = 2*py + kh;            tc = 2*px + kw; }
                    else         { tr = ((py+kh-1)>>1) + 1;   tc = ((px+kw-1)>>1) + 1; }
                    xv[kh*3+kw] = ilds[ck*R*C + tr*C + tc];
                }
            #pragma unroll
            for (int k = 0; k < 9; ++k) {
                #pragma unroll
                for (int g = 0; g < GRP4; ++g) {
                    const float4 w = *reinterpret_cast<const float4*>(
                        &wlds[(ck*9+k)*CO_BLK + (grp*GRP4+g)*4]);
                    acc[g*4+0] += xv[k]*w.x;
                    acc[g*4+1] += xv[k]*w.y;
                    acc[g*4+2] += xv[k]*w.z;
                    acc[g*4+3] += xv[k]*w.w;
                }
            }
        }
        __syncthreads();
    }

    // ---- epilogue: bias + relu + store ----
    const int oh = oh0 + py, ow = ow0 + px;
    #pragma unroll
    for (int g = 0; g < GRP4; ++g) {
        #pragma unroll
        for (int j = 0; j < 4; ++j) {
            int co = co0 + grp*ACC + g*4 + j;
            float v = acc[g*4+j] + Bb[co];
            v = fmaxf(v, 0.f);
            out[((long)n*COUT + co)*HO*WO + oh*WO + ow] = v;
        }
    }
}

// ---- classifier path ----
__global__ __launch_bounds__(256) void pool_kernel(const float* __restrict__ feats,
                                                   float* __restrict__ pooled)
{
    int i = blockIdx.x*256 + threadIdx.x;  // i = n*512 + co
    if (i < 64*512) {
        const float* f = feats + (long)i*16;
        float s = 0.f;
        #pragma unroll
        for (int j = 0; j < 16; ++j) s += f[j];
        pooled[i] = s * (1.f/16.f);
    }
}

__global__ __launch_bounds__(256) void fc1_kernel(const float* __restrict__ pooled,
                                                  const float* __restrict__ Wc1,
                                                  const float* __restrict__ bc1,
                                                  float* __restrict__ hidden)
{
    int i = blockIdx.x*256 + threadIdx.x;  // i = n*128 + j
    if (i < 64*128) {
        int n = i/128, j = i%128;
        const float* p = pooled + n*512;
        const float* w = Wc1 + j*512;
        float s = 0.f;
        for (int k = 0; k < 512; ++k) s += p[k]*w[k];
        hidden[i] = fmaxf(s + bc1[j], 0.f);
    }
}

__global__ __launch_bounds__(64) void fc2_kernel(const float* __restrict__ hidden,
                                                 const float* __restrict__ Wc2,
                                                 const float* __restrict__ bc2,
                                                 float* __restrict__ out,
                                                 int* __restrict__ cls_i)
{
    int n = blockIdx.x;
    int j = threadIdx.x;
    __shared__ float lg[5];
    if (j < 5) {
        const float* h = hidden + n*128;
        const float* w = Wc2 + j*128;
        float s = 0.f;
        for (int k = 0; k < 128; ++k) s += h[k]*w[k];
        s += bc2[j];
        out[n*5 + j] = s;        // logits
        lg[j] = s;
    }
    __syncthreads();
    if (j == 0) {
        int am = 0; float best = lg[0];
        #pragma unroll
        for (int k = 1; k < 5; ++k) if (lg[k] > best) { best = lg[k]; am = k; }
        out[320 + n] = (float)am;   // cls as float
        cls_i[n] = am;
    }
}

// ---- 1x1 head (no relu) ----
__global__ __launch_bounds__(256) void head_kernel(const float* __restrict__ d5,
                                                   const float* __restrict__ Wh,
                                                   const float* __restrict__ bh,
                                                   const int* __restrict__ cls_i,
                                                   float* __restrict__ seg)
{
    int n = blockIdx.y;
    int p = blockIdx.x*256 + threadIdx.x;  // 0..16383
    __shared__ float w[85];                 // [co*16+ci], bias at 80+
    int e = cls_i[n];
    if (threadIdx.x < 80) w[threadIdx.x] = Wh[(long)e*80 + threadIdx.x];
    if (threadIdx.x < 5)  w[80+threadIdx.x] = bh[e*5 + threadIdx.x];
    __syncthreads();
    float x[16];
    const float* dp = d5 + (long)n*16*16384 + p;
    #pragma unroll
    for (int ci = 0; ci < 16; ++ci) x[ci] = dp[ci*16384];
    #pragma unroll
    for (int co = 0; co < 5; ++co) {
        float s = w[80+co];
        #pragma unroll
        for (int ci = 0; ci < 16; ++ci) s += x[ci]*w[co*16+ci];
        seg[((long)n*5 + co)*16384 + p] = s;
    }
}

extern "C" void kernel_launch(void* const* d_in, const int* in_sizes, int n_in,
                              void* d_out, int out_size, void* d_ws, size_t ws_size,
                              hipStream_t stream)
{
    const float* x   = (const float*)d_in[0];
    const float* Wb1 = (const float*)d_in[1];  const float* bb1 = (const float*)d_in[2];
    const float* Wb2 = (const float*)d_in[3];  const float* bb2 = (const float*)d_in[4];
    const float* Wb3 = (const float*)d_in[5];  const float* bb3 = (const float*)d_in[6];
    const float* Wb4 = (const float*)d_in[7];  const float* bb4 = (const float*)d_in[8];
    const float* Wb5 = (const float*)d_in[9];  const float* bb5 = (const float*)d_in[10];
    const float* Wc1 = (const float*)d_in[11]; const float* bc1 = (const float*)d_in[12];
    const float* Wc2 = (const float*)d_in[13]; const float* bc2 = (const float*)d_in[14];
    const float* We1 = (const float*)d_in[15]; const float* be1 = (const float*)d_in[16];
    const float* We2 = (const float*)d_in[17]; const float* be2 = (const float*)d_in[18];
    const float* We3 = (const float*)d_in[19]; const float* be3 = (const float*)d_in[20];
    const float* We4 = (const float*)d_in[21]; const float* be4 = (const float*)d_in[22];
    const float* We5 = (const float*)d_in[23]; const float* be5 = (const float*)d_in[24];
    const float* We6 = (const float*)d_in[25]; const float* be6 = (const float*)d_in[26];

    float* out = (float*)d_out;

    // workspace layout (fp32 elements)
    float* A      = (float*)d_ws;             // 16,777,216 (h1 / h3 / d1 / d3 / d5)
    float* B      = A + 16777216;             //  8,388,608 (h2 / h4 / d2 / d4)
    float* FEATS  = B + 8388608;              //    524,288
    float* pooled = FEATS + 524288;           //     32,768
    float* hidden = pooled + 32768;           //      8,192
    int*   cls_i  = (int*)(hidden + 8192);    //         64

    // ---- backbone (stride-2 convs + relu) ----
    hipLaunchKernelGGL((conv3x3_kernel<3,  64, 64,64, 8,8, 32,8,3,0>), dim3(64, 2,64), dim3(256), 0, stream, x, Wb1, bb1, A,     cls_i, 0, 0);
    hipLaunchKernelGGL((conv3x3_kernel<64, 128,32,32, 8,8, 32,8,8,0>), dim3(16, 4,64), dim3(256), 0, stream, A, Wb2, bb2, B,     cls_i, 0, 0);
    hipLaunchKernelGGL((conv3x3_kernel<128,256,16,16, 8,8, 32,8,8,0>), dim3(4,  8,64), dim3(256), 0, stream, B, Wb3, bb3, A,     cls_i, 0, 0);
    hipLaunchKernelGGL((conv3x3_kernel<256,512, 8, 8, 8,8, 32,8,8,0>), dim3(1, 16,64), dim3(256), 0, stream, A, Wb4, bb4, B,     cls_i, 0, 0);
    hipLaunchKernelGGL((conv3x3_kernel<512,512, 4, 4, 4,4,128,8,8,0>), dim3(1,  4,64), dim3(256), 0, stream, B, Wb5, bb5, FEATS, cls_i, 0, 0);

    // ---- classifier ----
    hipLaunchKernelGGL(pool_kernel, dim3(128), dim3(256), 0, stream, FEATS, pooled);
    hipLaunchKernelGGL(fc1_kernel,  dim3(32),  dim3(256), 0, stream, pooled, Wc1, bc1, hidden);
    hipLaunchKernelGGL(fc2_kernel,  dim3(64),  dim3(64),  0, stream, hidden, Wc2, bc2, out, cls_i);

    // ---- expert decoder (fused up2 + conv3x3 + relu), per-sample weights ----
    hipLaunchKernelGGL((conv3x3_kernel<512,256,  8,  8, 8,8,32,8,8,1>), dim3(1,  8,64), dim3(256), 0, stream, FEATS, We1, be1, A, cls_i, 256*512*9, 256);
    hipLaunchKernelGGL((conv3x3_kernel<256,128, 16, 16, 8,8,32,8,8,1>), dim3(4,  4,64), dim3(256), 0, stream, A,     We2, be2, B, cls_i, 128*256*9, 128);
    hipLaunchKernelGGL((conv3x3_kernel<128, 64, 32, 32, 8,8,32,8,8,1>), dim3(16, 2,64), dim3(256), 0, stream, B,     We3, be3, A, cls_i,  64*128*9,  64);
    hipLaunchKernelGGL((conv3x3_kernel< 64, 32, 64, 64, 8,8,32,8,8,1>), dim3(64, 1,64), dim3(256), 0, stream, A,     We4, be4, B, cls_i,  32*64*9,   32);
    hipLaunchKernelGGL((conv3x3_kernel< 32, 16,128,128, 8,8,16,4,8,1>), dim3(256,1,64), dim3(256), 0, stream, B,     We5, be5, A, cls_i,  16*32*9,   16);

    // ---- 1x1 head -> seg ----
    hipLaunchKernelGGL(head_kernel, dim3(64,64), dim3(256), 0, stream, A, We6, be6, cls_i, out + 384);
}

// Round 2
// 1717.933 us; speedup vs baseline: 1.6262x; 1.6262x over previous
//
#include <hip/hip_runtime.h>
#include <hip/hip_bf16.h>

// ---------------------------------------------------------------------------
// R2: fp32 backbone (conv5 occupancy fix) + bf16-MFMA implicit-GEMM decoder.
// ---------------------------------------------------------------------------

typedef __attribute__((ext_vector_type(8))) short bf16x8;   // 8 bf16 = 4 VGPRs
typedef __attribute__((ext_vector_type(4))) float f32x4;

static __device__ __forceinline__ unsigned short f2bf(float f) {
    __hip_bfloat16 h = __float2bfloat16(f);
    return *reinterpret_cast<unsigned short*>(&h);
}

// ===================== fp32 direct conv (backbone) =========================
// MODE 0: stride-2 downsample conv, SAME (pad bottom/right only): ih = 2*oh+kh
template<int CIN,int COUT,int HO,int WO,int TH,int TW,int CO_BLK,int ACC,int CK,int MODE>
__global__ __launch_bounds__(256)
void conv3x3_kernel(const float* __restrict__ in, const float* __restrict__ W,
                    const float* __restrict__ Bias, float* __restrict__ out)
{
    constexpr int HI = (MODE==0) ? HO*2 : HO/2;
    constexpr int WI = (MODE==0) ? WO*2 : WO/2;
    constexpr int R  = (MODE==0) ? 2*TH+1 : TH/2+2;
    constexpr int C  = (MODE==0) ? 2*TW+1 : TW/2+2;
    constexpr int SP = TH*TW;
    constexpr int NGRP = CO_BLK/ACC;
    constexpr int GRP4 = ACC/4;
    static_assert(SP*NGRP == 256, "block must be 256 threads");

    __shared__ __align__(16) float ilds[CK*R*C];
    __shared__ __align__(16) float wlds[CK*9*CO_BLK];

    const int n   = blockIdx.z;
    const int co0 = blockIdx.y * CO_BLK;
    constexpr int TILES_X = WO/TW;
    const int ty = blockIdx.x / TILES_X, tx = blockIdx.x % TILES_X;
    const int oh0 = ty*TH, ow0 = tx*TW;

    const int t   = threadIdx.x;
    const int p   = t % SP;
    const int grp = t / SP;
    const int py  = p / TW, px = p % TW;

    float acc[ACC];
    #pragma unroll
    for (int i=0;i<ACC;i++) acc[i] = 0.f;

    const int r0 = 2*oh0;
    const int c0 = 2*ow0;

    for (int ci0 = 0; ci0 < CIN; ci0 += CK) {
        const float* ibase = in + ((long)n*CIN + ci0)*HI*WI;
        for (int idx = t; idx < CK*R*C; idx += 256) {
            int ck = idx/(R*C); int rc = idx%(R*C);
            int r = rc/C, c = rc%C;
            int ih = r0 + r, iw = c0 + c;
            float v = 0.f;
            if (ih >= 0 && ih < HI && iw >= 0 && iw < WI)
                v = ibase[(long)ck*HI*WI + ih*WI + iw];
            ilds[idx] = v;
        }
        for (int idx = t; idx < CO_BLK*CK*9; idx += 256) {
            int co = idx % CO_BLK; int rem = idx / CO_BLK;
            wlds[rem*CO_BLK + co] = W[(long)(co0+co)*CIN*9 + ci0*9 + rem];
        }
        __syncthreads();

        #pragma unroll
        for (int ck = 0; ck < CK; ++ck) {
            float xv[9];
            #pragma unroll
            for (int kh = 0; kh < 3; ++kh)
                #pragma unroll
                for (int kw = 0; kw < 3; ++kw)
                    xv[kh*3+kw] = ilds[ck*R*C + (2*py+kh)*C + 2*px+kw];
            #pragma unroll
            for (int k = 0; k < 9; ++k) {
                #pragma unroll
                for (int g = 0; g < GRP4; ++g) {
                    const float4 w = *reinterpret_cast<const float4*>(
                        &wlds[(ck*9+k)*CO_BLK + (grp*GRP4+g)*4]);
                    acc[g*4+0] += xv[k]*w.x;
                    acc[g*4+1] += xv[k]*w.y;
                    acc[g*4+2] += xv[k]*w.z;
                    acc[g*4+3] += xv[k]*w.w;
                }
            }
        }
        __syncthreads();
    }

    const int oh = oh0 + py, ow = ow0 + px;
    #pragma unroll
    for (int g = 0; g < GRP4; ++g) {
        #pragma unroll
        for (int j = 0; j < 4; ++j) {
            int co = co0 + grp*ACC + g*4 + j;
            float v = acc[g*4+j] + Bias[co];
            v = fmaxf(v, 0.f);
            out[((long)n*COUT + co)*HO*WO + oh*WO + ow] = v;
        }
    }
}

// ===================== classifier path =====================================
__global__ __launch_bounds__(256) void pool_kernel(const float* __restrict__ feats,
                                                   float* __restrict__ pooled)
{
    int i = blockIdx.x*256 + threadIdx.x;
    if (i < 64*512) {
        const float* f = feats + (long)i*16;
        float s = 0.f;
        #pragma unroll
        for (int j = 0; j < 16; ++j) s += f[j];
        pooled[i] = s * (1.f/16.f);
    }
}

__global__ __launch_bounds__(256) void fc1_kernel(const float* __restrict__ pooled,
                                                  const float* __restrict__ Wc1,
                                                  const float* __restrict__ bc1,
                                                  float* __restrict__ hidden)
{
    int i = blockIdx.x*256 + threadIdx.x;
    if (i < 64*128) {
        int n = i/128, j = i%128;
        const float* p = pooled + n*512;
        const float* w = Wc1 + j*512;
        float s = 0.f;
        for (int k = 0; k < 512; ++k) s += p[k]*w[k];
        hidden[i] = fmaxf(s + bc1[j], 0.f);
    }
}

__global__ __launch_bounds__(64) void fc2_kernel(const float* __restrict__ hidden,
                                                 const float* __restrict__ Wc2,
                                                 const float* __restrict__ bc2,
                                                 float* __restrict__ out,
                                                 int* __restrict__ cls_i)
{
    int n = blockIdx.x;
    int j = threadIdx.x;
    __shared__ float lg[5];
    if (j < 5) {
        const float* h = hidden + n*128;
        const float* w = Wc2 + j*128;
        float s = 0.f;
        for (int k = 0; k < 128; ++k) s += h[k]*w[k];
        s += bc2[j];
        out[n*5 + j] = s;
        lg[j] = s;
    }
    __syncthreads();
    if (j == 0) {
        int am = 0; float best = lg[0];
        #pragma unroll
        for (int k = 1; k < 5; ++k) if (lg[k] > best) { best = lg[k]; am = k; }
        out[320 + n] = (float)am;
        cls_i[n] = am;
    }
}

// ===================== layout transforms ===================================
// feats NCHW fp32 [64][512][4][4] -> NHWC bf16 [64][4][4][512]
__global__ __launch_bounds__(256) void feats2hwc_kernel(const float* __restrict__ f,
                                                        unsigned short* __restrict__ o)
{
    int idx = blockIdx.x*256 + threadIdx.x;
    if (idx < 64*16*512) {
        int ci = idx & 511, pix = (idx >> 9) & 15, n = idx >> 13;
        o[idx] = f2bf(f[((long)n*512 + ci)*16 + pix]);
    }
}

// We[e][co][ci][3][3] fp32 -> WT[e][co][9][ci] bf16   (one block per (e,co))
template<int CI>
__global__ __launch_bounds__(256)
void wtrans_kernel(const float* __restrict__ src, unsigned short* __restrict__ dst)
{
    __shared__ float buf[CI*9];
    const long blk = blockIdx.x;
    const float* s = src + blk*(CI*9);
    for (int i = threadIdx.x; i < CI*9; i += 256) buf[i] = s[i];
    __syncthreads();
    unsigned short* d = dst + blk*(CI*9);
    for (int i = threadIdx.x; i < CI*9; i += 256) {
        int k = i / CI, ci = i % CI;
        d[i] = f2bf(buf[ci*9 + k]);
    }
}

// ===================== bf16 MFMA decoder conv ==============================
// in  : NHWC bf16 [64][HI][HI][CI]   (HI = HO/2, up2 fused into indexing)
// WT  : [E][CO][9][CI] bf16 (pre-transposed)
// out : NHWC bf16 [64][HO][HO][CO], relu
// Block = 256 thr = 4 waves. Block tile = CO_T x (TH*TW). Wave handles S
// 2x8-spatial subtiles x NT co-subtiles of 16.
template<int CI,int CO,int HO,int TH,int TW,int CO_T,int CK>
__global__ __launch_bounds__(256)
void dec_conv_kernel(const unsigned short* __restrict__ in,
                     const unsigned short* __restrict__ WT,
                     const float* __restrict__ Be,
                     const int* __restrict__ cls_i,
                     unsigned short* __restrict__ out)
{
    constexpr int HI = HO/2;
    constexpr int R = TH/2 + 2, C = TW/2 + 2;
    constexpr int PITCH = CK + 8;          // bf16 units; pixel pitch = 4 banks mod 32
    constexpr int NT = CO_T/16;
    constexpr int S  = (TH*TW)/64;         // spatial subtiles per wave
    constexpr int SXT = TW/8;

    __shared__ __align__(16) unsigned short ilds[R*C*PITCH];

    const int n = blockIdx.z;
    const int e = cls_i[n];
    const int co0 = blockIdx.y * CO_T;
    constexpr int TILES_X = HO/TW;
    const int ty = blockIdx.x / TILES_X, tx = blockIdx.x % TILES_X;
    const int oh0 = ty*TH, ow0 = tx*TW;
    const int ih0 = oh0/2 - 1, iw0 = ow0/2 - 1;

    const int t = threadIdx.x;
    const int w = t >> 6;
    const int lane = t & 63;
    const int s = lane & 15;       // A-row m / B-col n / D-col
    const int q = lane >> 4;       // K-quad / D row-quad

    const unsigned short* Wbase = WT + ((long)e*CO + co0)*9*CI;
    const unsigned short* inN   = in + (long)n*HI*HI*CI;

    f32x4 acc[S][NT];
    #pragma unroll
    for (int si = 0; si < S; ++si)
        #pragma unroll
        for (int tn = 0; tn < NT; ++tn)
            acc[si][tn] = (f32x4){0.f,0.f,0.f,0.f};

    int dy[S], dx[S];
    #pragma unroll
    for (int si = 0; si < S; ++si) {
        int sub = w + si*4;
        int sy = sub / SXT, sx = sub % SXT;
        dy[si] = sy*2 + (s >> 3);
        dx[si] = sx*8 + (s & 7);
    }

    for (int ci0 = 0; ci0 < CI; ci0 += CK) {
        // ---- stage input tile (uint4 = 8 bf16), zero-padded ----
        constexpr int C8 = CK/8;
        for (int i8 = t; i8 < R*C*C8; i8 += 256) {
            int pix = i8 / C8, cs = i8 % C8;
            int r = pix / C, c = pix % C;
            int ih = ih0 + r, iw = iw0 + c;
            uint4 v = {0u,0u,0u,0u};
            if (ih >= 0 && ih < HI && iw >= 0 && iw < HI)
                v = *reinterpret_cast<const uint4*>(&inN[((long)ih*HI + iw)*CI + ci0 + cs*8]);
            *reinterpret_cast<uint4*>(&ilds[pix*PITCH + cs*8]) = v;
        }
        __syncthreads();

        #pragma unroll
        for (int kh = 0; kh < 3; ++kh)
        #pragma unroll
        for (int kw = 0; kw < 3; ++kw) {
            const int k = kh*3 + kw;
            #pragma unroll
            for (int ckq = 0; ckq < CK/32; ++ckq) {
                bf16x8 a[NT];
                #pragma unroll
                for (int tn = 0; tn < NT; ++tn)
                    a[tn] = *reinterpret_cast<const bf16x8*>(
                        &Wbase[((long)(tn*16 + s)*9 + k)*CI + ci0 + ckq*32 + q*8]);
                #pragma unroll
                for (int si = 0; si < S; ++si) {
                    int ihr = ((dy[si] + kh - 1) >> 1) + 1;
                    int iwr = ((dx[si] + kw - 1) >> 1) + 1;
                    bf16x8 b = *reinterpret_cast<const bf16x8*>(
                        &ilds[(ihr*C + iwr)*PITCH + ckq*32 + q*8]);
                    #pragma unroll
                    for (int tn = 0; tn < NT; ++tn)
                        acc[si][tn] = __builtin_amdgcn_mfma_f32_16x16x32_bf16(
                            a[tn], b, acc[si][tn], 0, 0, 0);
                }
            }
        }
        __syncthreads();
    }

    // ---- epilogue: bias + relu + bf16 NHWC store ----
    #pragma unroll
    for (int si = 0; si < S; ++si) {
        int oh = oh0 + dy[si], ow = ow0 + dx[si];
        #pragma unroll
        for (int tn = 0; tn < NT; ++tn) {
            int co_b = co0 + tn*16 + q*4;
            ushort4 st;
            #pragma unroll
            for (int r = 0; r < 4; ++r) {
                float v = acc[si][tn][r] + Be[e*CO + co_b + r];
                v = fmaxf(v, 0.f);
                ((unsigned short*)&st)[r] = f2bf(v);
            }
            *reinterpret_cast<ushort4*>(&out[(((long)n*HO + oh)*HO + ow)*CO + co_b]) = st;
        }
    }
}

// ===================== 1x1 head: NHWC bf16 -> NCHW fp32 ====================
__global__ __launch_bounds__(256) void head_kernel(const unsigned short* __restrict__ d5,
                                                   const float* __restrict__ Wh,
                                                   const float* __restrict__ bh,
                                                   const int* __restrict__ cls_i,
                                                   float* __restrict__ seg)
{
    int n = blockIdx.y;
    int p = blockIdx.x*256 + threadIdx.x;
    __shared__ float w[85];
    int e = cls_i[n];
    if (threadIdx.x < 80) w[threadIdx.x] = Wh[(long)e*80 + threadIdx.x];
    if (threadIdx.x < 5)  w[80+threadIdx.x] = bh[e*5 + threadIdx.x];
    __syncthreads();
    const unsigned short* dp = d5 + ((long)n*16384 + p)*16;
    uint4 u0 = *reinterpret_cast<const uint4*>(dp);
    uint4 u1 = *reinterpret_cast<const uint4*>(dp + 8);
    float x[16];
    unsigned int uu[4] = {u0.x, u0.y, u0.z, u0.w};
    unsigned int vv[4] = {u1.x, u1.y, u1.z, u1.w};
    #pragma unroll
    for (int i = 0; i < 4; ++i) {
        x[2*i+0] = __uint_as_float(uu[i] << 16);
        x[2*i+1] = __uint_as_float(uu[i] & 0xffff0000u);
        x[8+2*i+0] = __uint_as_float(vv[i] << 16);
        x[8+2*i+1] = __uint_as_float(vv[i] & 0xffff0000u);
    }
    #pragma unroll
    for (int co = 0; co < 5; ++co) {
        float sacc = w[80+co];
        #pragma unroll
        for (int ci = 0; ci < 16; ++ci) sacc += x[ci]*w[co*16+ci];
        seg[((long)n*5 + co)*16384 + p] = sacc;
    }
}

// ===========================================================================
extern "C" void kernel_launch(void* const* d_in, const int* in_sizes, int n_in,
                              void* d_out, int out_size, void* d_ws, size_t ws_size,
                              hipStream_t stream)
{
    const float* x   = (const float*)d_in[0];
    const float* Wb1 = (const float*)d_in[1];  const float* bb1 = (const float*)d_in[2];
    const float* Wb2 = (const float*)d_in[3];  const float* bb2 = (const float*)d_in[4];
    const float* Wb3 = (const float*)d_in[5];  const float* bb3 = (const float*)d_in[6];
    const float* Wb4 = (const float*)d_in[7];  const float* bb4 = (const float*)d_in[8];
    const float* Wb5 = (const float*)d_in[9];  const float* bb5 = (const float*)d_in[10];
    const float* Wc1 = (const float*)d_in[11]; const float* bc1 = (const float*)d_in[12];
    const float* Wc2 = (const float*)d_in[13]; const float* bc2 = (const float*)d_in[14];
    const float* We1 = (const float*)d_in[15]; const float* be1 = (const float*)d_in[16];
    const float* We2 = (const float*)d_in[17]; const float* be2 = (const float*)d_in[18];
    const float* We3 = (const float*)d_in[19]; const float* be3 = (const float*)d_in[20];
    const float* We4 = (const float*)d_in[21]; const float* be4 = (const float*)d_in[22];
    const float* We5 = (const float*)d_in[23]; const float* be5 = (const float*)d_in[24];
    const float* We6 = (const float*)d_in[25]; const float* be6 = (const float*)d_in[26];

    float* out = (float*)d_out;

    // ---- workspace layout ----
    char* wsb = (char*)d_ws;
    float* A = (float*)wsb;                             // 64 MiB fp32 region
    float* B = A + 16777216;                            // 32 MiB fp32 region
    float* FEATS  = B + 8388608;                        // 2 MiB
    float* pooled = FEATS + 524288;
    float* hidden = pooled + 32768;
    int*   cls_i  = (int*)(hidden + 8192);

    // bf16 overlays (A region free after conv5; B region free after conv5)
    unsigned short* FHWC = (unsigned short*)wsb;                       // 1 MiB
    unsigned short* P    = (unsigned short*)(wsb + 1048576);           // 33.5 MB
    unsigned short* Q    = (unsigned short*)(wsb + 34603008);          // 16.8 MB
    char* Bb = (char*)(A + 16777216);
    unsigned short* WT1 = (unsigned short*)Bb;                         // 5*256*9*512
    unsigned short* WT2 = WT1 + 5898240;                               // 5*128*9*256
    unsigned short* WT3 = WT2 + 1474560;                               // 5*64*9*128
    unsigned short* WT4 = WT3 + 368640;                                // 5*32*9*64
    unsigned short* WT5 = WT4 + 92160;                                 // 5*16*9*32

    // ---- backbone (fp32 stride-2 convs + relu) ----
    hipLaunchKernelGGL((conv3x3_kernel<3,  64, 64,64, 8,8, 32,8,3,0>), dim3(64, 2,64), dim3(256), 0, stream, x, Wb1, bb1, A);
    hipLaunchKernelGGL((conv3x3_kernel<64, 128,32,32, 8,8, 32,8,8,0>), dim3(16, 4,64), dim3(256), 0, stream, A, Wb2, bb2, B);
    hipLaunchKernelGGL((conv3x3_kernel<128,256,16,16, 8,8, 32,8,8,0>), dim3(4,  8,64), dim3(256), 0, stream, B, Wb3, bb3, A);
    hipLaunchKernelGGL((conv3x3_kernel<256,512, 8, 8, 8,8, 32,8,8,0>), dim3(1, 16,64), dim3(256), 0, stream, A, Wb4, bb4, B);
    hipLaunchKernelGGL((conv3x3_kernel<512,512, 4, 4, 4,4, 64,4,8,0>), dim3(1,  8,64), dim3(256), 0, stream, B, Wb5, bb5, FEATS);

    // ---- classifier ----
    hipLaunchKernelGGL(pool_kernel, dim3(128), dim3(256), 0, stream, FEATS, pooled);
    hipLaunchKernelGGL(fc1_kernel,  dim3(32),  dim3(256), 0, stream, pooled, Wc1, bc1, hidden);
    hipLaunchKernelGGL(fc2_kernel,  dim3(64),  dim3(64),  0, stream, hidden, Wc2, bc2, out, cls_i);

    // ---- layout transforms (A and B fp32 regions are dead now) ----
    hipLaunchKernelGGL(feats2hwc_kernel, dim3(2048), dim3(256), 0, stream, FEATS, FHWC);
    hipLaunchKernelGGL((wtrans_kernel<512>), dim3(5*256), dim3(256), 0, stream, We1, WT1);
    hipLaunchKernelGGL((wtrans_kernel<256>), dim3(5*128), dim3(256), 0, stream, We2, WT2);
    hipLaunchKernelGGL((wtrans_kernel<128>), dim3(5*64),  dim3(256), 0, stream, We3, WT3);
    hipLaunchKernelGGL((wtrans_kernel<64>),  dim3(5*32),  dim3(256), 0, stream, We4, WT4);
    hipLaunchKernelGGL((wtrans_kernel<32>),  dim3(5*16),  dim3(256), 0, stream, We5, WT5);

    // ---- bf16 MFMA decoder:  FHWC -> P -> Q -> P -> Q -> P ----
    hipLaunchKernelGGL((dec_conv_kernel<512,256,  8,  8, 8, 64,64>), dim3(1,  4,64), dim3(256), 0, stream, FHWC, WT1, be1, cls_i, P);
    hipLaunchKernelGGL((dec_conv_kernel<256,128, 16,  8, 8, 64,64>), dim3(4,  2,64), dim3(256), 0, stream, P,    WT2, be2, cls_i, Q);
    hipLaunchKernelGGL((dec_conv_kernel<128, 64, 32,  8, 8, 64,64>), dim3(16, 1,64), dim3(256), 0, stream, Q,    WT3, be3, cls_i, P);
    hipLaunchKernelGGL((dec_conv_kernel< 64, 32, 64, 16,16, 32,64>), dim3(16, 1,64), dim3(256), 0, stream, P,    WT4, be4, cls_i, Q);
    hipLaunchKernelGGL((dec_conv_kernel< 32, 16,128, 16,16, 16,32>), dim3(64, 1,64), dim3(256), 0, stream, Q,    WT5, be5, cls_i, P);

    // ---- 1x1 head -> seg (NCHW fp32) ----
    hipLaunchKernelGGL(head_kernel, dim3(64,64), dim3(256), 0, stream, P, We6, be6, cls_i, out + 384);
}

// Round 3
// 1121.484 us; speedup vs baseline: 2.4910x; 1.5318x over previous
//
#include <hip/hip_runtime.h>
#include <hip/hip_bf16.h>

// ---------------------------------------------------------------------------
// R3: split-bf16 (hi+lo, 3xMFMA) backbone conv2-5 + bf16 MFMA decoder.
// conv1 stays fp32-direct (CIN=3), writes split NHWC hi/lo in epilogue.
// ---------------------------------------------------------------------------

typedef __attribute__((ext_vector_type(8))) short bf16x8;   // 8 bf16 = 4 VGPRs
typedef __attribute__((ext_vector_type(4))) float f32x4;

static __device__ __forceinline__ unsigned short f2bf(float f) {
    __hip_bfloat16 h = __float2bfloat16(f);
    return *reinterpret_cast<unsigned short*>(&h);
}
static __device__ __forceinline__ float bf2f(unsigned short u) {
    return __uint_as_float(((unsigned int)u) << 16);
}

// ===================== conv1: fp32 direct, split NHWC output ===============
// in x NCHW fp32 [64][3][128][128]; out hi/lo NHWC bf16 [64][64][64][64]
__global__ __launch_bounds__(256)
void conv1_kernel(const float* __restrict__ in, const float* __restrict__ W,
                  const float* __restrict__ Bias,
                  unsigned short* __restrict__ out_hi,
                  unsigned short* __restrict__ out_lo)
{
    constexpr int R = 17, C = 17;
    __shared__ float ilds[3*R*C];
    __shared__ float wlds[27*32];
    const int n = blockIdx.z, co0 = blockIdx.y*32;
    const int ty = blockIdx.x >> 3, tx = blockIdx.x & 7;
    const int oh0 = ty*8, ow0 = tx*8;
    const int t = threadIdx.x, p = t & 63, grp = t >> 6;
    const int py = p >> 3, px = p & 7;
    const int r0 = 2*oh0, c0 = 2*ow0;

    const float* ibase = in + (long)n*3*16384;
    for (int idx = t; idx < 3*R*C; idx += 256) {
        int ck = idx/(R*C), rc = idx%(R*C);
        int r = rc/C, c = rc%C;
        int ih = r0+r, iw = c0+c;
        float v = 0.f;
        if (ih < 128 && iw < 128) v = ibase[ck*16384 + ih*128 + iw];
        ilds[idx] = v;
    }
    for (int idx = t; idx < 32*27; idx += 256) {
        int co = idx & 31, rem = idx >> 5;
        wlds[rem*32 + co] = W[(co0+co)*27 + rem];
    }
    __syncthreads();

    float acc[8];
    #pragma unroll
    for (int i=0;i<8;i++) acc[i]=0.f;

    #pragma unroll
    for (int ck = 0; ck < 3; ++ck) {
        float xv[9];
        #pragma unroll
        for (int kh = 0; kh < 3; ++kh)
            #pragma unroll
            for (int kw = 0; kw < 3; ++kw)
                xv[kh*3+kw] = ilds[ck*289 + (2*py+kh)*17 + 2*px+kw];
        #pragma unroll
        for (int k = 0; k < 9; ++k) {
            #pragma unroll
            for (int g = 0; g < 2; ++g) {
                const float4 w = *reinterpret_cast<const float4*>(
                    &wlds[(ck*9+k)*32 + grp*8 + g*4]);
                acc[g*4+0] += xv[k]*w.x;
                acc[g*4+1] += xv[k]*w.y;
                acc[g*4+2] += xv[k]*w.z;
                acc[g*4+3] += xv[k]*w.w;
            }
        }
    }

    const long obase = (((long)n*64 + oh0+py)*64 + ow0+px)*64 + co0 + grp*8;
    #pragma unroll
    for (int g = 0; g < 2; ++g) {
        ushort4 sh, sl;
        #pragma unroll
        for (int j = 0; j < 4; ++j) {
            int co = co0 + grp*8 + g*4 + j;
            float v = fmaxf(acc[g*4+j] + Bias[co], 0.f);
            unsigned short h = f2bf(v);
            ((unsigned short*)&sh)[j] = h;
            ((unsigned short*)&sl)[j] = f2bf(v - bf2f(h));
        }
        *reinterpret_cast<ushort4*>(&out_hi[obase + g*4]) = sh;
        *reinterpret_cast<ushort4*>(&out_lo[obase + g*4]) = sl;
    }
}

// ===================== split-bf16 MFMA stride-2 conv (backbone 2-5) ========
// in  : NHWC hi/lo bf16 [64][HI][HI][CI], HI=2*HO
// W   : hi/lo [CO][9][CI] bf16 (pre-transposed+split)
// out : NHWC hi/lo bf16 [64][HO][HO][CO], relu
template<int CI,int CO,int HO,int TH,int TW,int NT>
__global__ __launch_bounds__(256)
void bb_conv_s2(const unsigned short* __restrict__ in_hi,
                const unsigned short* __restrict__ in_lo,
                const unsigned short* __restrict__ Whi,
                const unsigned short* __restrict__ Wlo,
                const float* __restrict__ Bias,
                unsigned short* __restrict__ out_hi,
                unsigned short* __restrict__ out_lo)
{
    constexpr int HI = HO*2;
    constexpr int R = 2*TH+1, C = 2*TW+1;
    constexpr int CK = 32;
    constexpr int PITCH = CK + 8;              // 40 ushorts = 80 B
    constexpr int NSUB = (TH*TW)/16;           // 16-px subtiles per tile
    constexpr int SUBW = (TW>=8)?8:TW;
    constexpr int COG  = 4/NSUB;
    constexpr int CO_T = COG*NT*16;
    constexpr int SUBH = 16/SUBW;
    static_assert(NSUB==1 || NSUB==4, "tile is 16 or 64 px");

    __shared__ __align__(16) unsigned short hi_lds[R*C*PITCH];
    __shared__ __align__(16) unsigned short lo_lds[R*C*PITCH];

    const int n   = blockIdx.z;
    const int co0 = blockIdx.y * CO_T;
    constexpr int TILES_X = HO/TW;
    const int ty = blockIdx.x / TILES_X, tx = blockIdx.x % TILES_X;
    const int oh0 = ty*TH, ow0 = tx*TW;
    const int r0 = 2*oh0, c0 = 2*ow0;

    const int t = threadIdx.x;
    const int w = t >> 6, lane = t & 63;
    const int s = lane & 15, q = lane >> 4;
    const int sub = w % NSUB, cog = w / NSUB;
    const int dy = sub*SUBH + s/SUBW;
    const int dx = s % SUBW;

    const unsigned short* inHn = in_hi + (long)n*HI*HI*CI;
    const unsigned short* inLn = in_lo + (long)n*HI*HI*CI;

    // per-tn weight row base offsets (elements)
    int wrow[NT];
    #pragma unroll
    for (int tn = 0; tn < NT; ++tn)
        wrow[tn] = (co0 + cog*NT*16 + tn*16 + s)*9*CI + q*8;

    f32x4 acc[NT];
    #pragma unroll
    for (int tn = 0; tn < NT; ++tn) acc[tn] = (f32x4){0.f,0.f,0.f,0.f};

    for (int ci0 = 0; ci0 < CI; ci0 += CK) {
        // ---- stage hi & lo input tiles (uint4 = 8 bf16), zero-padded ----
        constexpr int C8 = CK/8;
        for (int i8 = t; i8 < R*C*C8; i8 += 256) {
            int pix = i8 / C8, cs = i8 % C8;
            int r = pix / C, c = pix % C;
            int ih = r0 + r, iw = c0 + c;
            uint4 vh = {0u,0u,0u,0u}, vl = {0u,0u,0u,0u};
            if (ih < HI && iw < HI) {
                long off = ((long)ih*HI + iw)*CI + ci0 + cs*8;
                vh = *reinterpret_cast<const uint4*>(&inHn[off]);
                vl = *reinterpret_cast<const uint4*>(&inLn[off]);
            }
            *reinterpret_cast<uint4*>(&hi_lds[pix*PITCH + cs*8]) = vh;
            *reinterpret_cast<uint4*>(&lo_lds[pix*PITCH + cs*8]) = vl;
        }
        __syncthreads();

        #pragma unroll
        for (int kh = 0; kh < 3; ++kh)
        #pragma unroll
        for (int kw = 0; kw < 3; ++kw) {
            const int k = kh*3 + kw;
            const int pi = (2*dy + kh)*C + 2*dx + kw;
            bf16x8 bh = *reinterpret_cast<const bf16x8*>(&hi_lds[pi*PITCH + q*8]);
            bf16x8 bl = *reinterpret_cast<const bf16x8*>(&lo_lds[pi*PITCH + q*8]);
            #pragma unroll
            for (int tn = 0; tn < NT; ++tn) {
                const int wo = wrow[tn] + k*CI + ci0;
                bf16x8 ah = *reinterpret_cast<const bf16x8*>(&Whi[wo]);
                bf16x8 al = *reinterpret_cast<const bf16x8*>(&Wlo[wo]);
                acc[tn] = __builtin_amdgcn_mfma_f32_16x16x32_bf16(ah, bh, acc[tn], 0,0,0);
                acc[tn] = __builtin_amdgcn_mfma_f32_16x16x32_bf16(ah, bl, acc[tn], 0,0,0);
                acc[tn] = __builtin_amdgcn_mfma_f32_16x16x32_bf16(al, bh, acc[tn], 0,0,0);
            }
        }
        __syncthreads();
    }

    // ---- epilogue: bias + relu + split store ----
    const int oh = oh0 + dy, ow = ow0 + dx;
    #pragma unroll
    for (int tn = 0; tn < NT; ++tn) {
        int co_b = co0 + cog*NT*16 + tn*16 + q*4;
        ushort4 sh, sl;
        #pragma unroll
        for (int r = 0; r < 4; ++r) {
            float v = fmaxf(acc[tn][r] + Bias[co_b + r], 0.f);
            unsigned short h = f2bf(v);
            ((unsigned short*)&sh)[r] = h;
            ((unsigned short*)&sl)[r] = f2bf(v - bf2f(h));
        }
        long ob = (((long)n*HO + oh)*HO + ow)*CO + co_b;
        *reinterpret_cast<ushort4*>(&out_hi[ob]) = sh;
        *reinterpret_cast<ushort4*>(&out_lo[ob]) = sl;
    }
}

// ===================== weight transforms ===================================
// backbone: Wb [CO][CI][3][3] fp32 -> hi/lo [CO][9][CI] bf16 (one block per co)
template<int CI>
__global__ __launch_bounds__(256)
void wtrans_split_kernel(const float* __restrict__ src,
                         unsigned short* __restrict__ hi,
                         unsigned short* __restrict__ lo)
{
    __shared__ float buf[CI*9];
    const long blk = blockIdx.x;
    const float* sp = src + blk*(CI*9);
    for (int i = threadIdx.x; i < CI*9; i += 256) buf[i] = sp[i];
    __syncthreads();
    for (int i = threadIdx.x; i < CI*9; i += 256) {
        int k = i / CI, ci = i % CI;
        float v = buf[ci*9 + k];
        unsigned short h = f2bf(v);
        hi[blk*(CI*9) + i] = h;
        lo[blk*(CI*9) + i] = f2bf(v - bf2f(h));
    }
}

// decoder: We[e][co][ci][3][3] fp32 -> WT[e][co][9][ci] bf16 (block per (e,co))
template<int CI>
__global__ __launch_bounds__(256)
void wtrans_kernel(const float* __restrict__ src, unsigned short* __restrict__ dst)
{
    __shared__ float buf[CI*9];
    const long blk = blockIdx.x;
    const float* sp = src + blk*(CI*9);
    for (int i = threadIdx.x; i < CI*9; i += 256) buf[i] = sp[i];
    __syncthreads();
    unsigned short* d = dst + blk*(CI*9);
    for (int i = threadIdx.x; i < CI*9; i += 256) {
        int k = i / CI, ci = i % CI;
        d[i] = f2bf(buf[ci*9 + k]);
    }
}

// ===================== classifier path =====================================
// feats split NHWC [64][16][512]
__global__ __launch_bounds__(256) void pool_kernel(const unsigned short* __restrict__ fh,
                                                   const unsigned short* __restrict__ fl,
                                                   float* __restrict__ pooled)
{
    int i = blockIdx.x*256 + threadIdx.x;   // n*512 + ci
    if (i < 64*512) {
        int n = i >> 9, ci = i & 511;
        const unsigned short* ph = fh + (long)n*8192 + ci;
        const unsigned short* pl = fl + (long)n*8192 + ci;
        float sacc = 0.f;
        #pragma unroll
        for (int px = 0; px < 16; ++px)
            sacc += bf2f(ph[px*512]) + bf2f(pl[px*512]);
        pooled[i] = sacc * (1.f/16.f);
    }
}

__global__ __launch_bounds__(256) void fc1_kernel(const float* __restrict__ pooled,
                                                  const float* __restrict__ Wc1,
                                                  const float* __restrict__ bc1,
                                                  float* __restrict__ hidden)
{
    int i = blockIdx.x*256 + threadIdx.x;
    if (i < 64*128) {
        int n = i/128, j = i%128;
        const float* p = pooled + n*512;
        const float* w = Wc1 + j*512;
        float sacc = 0.f;
        for (int k = 0; k < 512; ++k) sacc += p[k]*w[k];
        hidden[i] = fmaxf(sacc + bc1[j], 0.f);
    }
}

__global__ __launch_bounds__(64) void fc2_kernel(const float* __restrict__ hidden,
                                                 const float* __restrict__ Wc2,
                                                 const float* __restrict__ bc2,
                                                 float* __restrict__ out,
                                                 int* __restrict__ cls_i)
{
    int n = blockIdx.x;
    int j = threadIdx.x;
    __shared__ float lg[5];
    if (j < 5) {
        const float* h = hidden + n*128;
        const float* w = Wc2 + j*128;
        float sacc = 0.f;
        for (int k = 0; k < 128; ++k) sacc += h[k]*w[k];
        sacc += bc2[j];
        out[n*5 + j] = sacc;
        lg[j] = sacc;
    }
    __syncthreads();
    if (j == 0) {
        int am = 0; float best = lg[0];
        #pragma unroll
        for (int k = 1; k < 5; ++k) if (lg[k] > best) { best = lg[k]; am = k; }
        out[320 + n] = (float)am;
        cls_i[n] = am;
    }
}

// ===================== bf16 MFMA decoder conv (unchanged from R2) ==========
template<int CI,int CO,int HO,int TH,int TW,int CO_T,int CK>
__global__ __launch_bounds__(256)
void dec_conv_kernel(const unsigned short* __restrict__ in,
                     const unsigned short* __restrict__ WT,
                     const float* __restrict__ Be,
                     const int* __restrict__ cls_i,
                     unsigned short* __restrict__ out)
{
    constexpr int HI = HO/2;
    constexpr int R = TH/2 + 2, C = TW/2 + 2;
    constexpr int PITCH = CK + 8;
    constexpr int NT = CO_T/16;
    constexpr int S  = (TH*TW)/64;
    constexpr int SXT = TW/8;

    __shared__ __align__(16) unsigned short ilds[R*C*PITCH];

    const int n = blockIdx.z;
    const int e = cls_i[n];
    const int co0 = blockIdx.y * CO_T;
    constexpr int TILES_X = HO/TW;
    const int ty = blockIdx.x / TILES_X, tx = blockIdx.x % TILES_X;
    const int oh0 = ty*TH, ow0 = tx*TW;
    const int ih0 = oh0/2 - 1, iw0 = ow0/2 - 1;

    const int t = threadIdx.x;
    const int w = t >> 6;
    const int lane = t & 63;
    const int s = lane & 15;
    const int q = lane >> 4;

    const unsigned short* Wbase = WT + ((long)e*CO + co0)*9*CI;
    const unsigned short* inN   = in + (long)n*HI*HI*CI;

    f32x4 acc[S][NT];
    #pragma unroll
    for (int si = 0; si < S; ++si)
        #pragma unroll
        for (int tn = 0; tn < NT; ++tn)
            acc[si][tn] = (f32x4){0.f,0.f,0.f,0.f};

    int dy[S], dx[S];
    #pragma unroll
    for (int si = 0; si < S; ++si) {
        int sub = w + si*4;
        int sy = sub / SXT, sx = sub % SXT;
        dy[si] = sy*2 + (s >> 3);
        dx[si] = sx*8 + (s & 7);
    }

    for (int ci0 = 0; ci0 < CI; ci0 += CK) {
        constexpr int C8 = CK/8;
        for (int i8 = t; i8 < R*C*C8; i8 += 256) {
            int pix = i8 / C8, cs = i8 % C8;
            int r = pix / C, c = pix % C;
            int ih = ih0 + r, iw = iw0 + c;
            uint4 v = {0u,0u,0u,0u};
            if (ih >= 0 && ih < HI && iw >= 0 && iw < HI)
                v = *reinterpret_cast<const uint4*>(&inN[((long)ih*HI + iw)*CI + ci0 + cs*8]);
            *reinterpret_cast<uint4*>(&ilds[pix*PITCH + cs*8]) = v;
        }
        __syncthreads();

        #pragma unroll
        for (int kh = 0; kh < 3; ++kh)
        #pragma unroll
        for (int kw = 0; kw < 3; ++kw) {
            const int k = kh*3 + kw;
            #pragma unroll
            for (int ckq = 0; ckq < CK/32; ++ckq) {
                bf16x8 a[NT];
                #pragma unroll
                for (int tn = 0; tn < NT; ++tn)
                    a[tn] = *reinterpret_cast<const bf16x8*>(
                        &Wbase[((long)(tn*16 + s)*9 + k)*CI + ci0 + ckq*32 + q*8]);
                #pragma unroll
                for (int si = 0; si < S; ++si) {
                    int ihr = ((dy[si] + kh - 1) >> 1) + 1;
                    int iwr = ((dx[si] + kw - 1) >> 1) + 1;
                    bf16x8 b = *reinterpret_cast<const bf16x8*>(
                        &ilds[(ihr*C + iwr)*PITCH + ckq*32 + q*8]);
                    #pragma unroll
                    for (int tn = 0; tn < NT; ++tn)
                        acc[si][tn] = __builtin_amdgcn_mfma_f32_16x16x32_bf16(
                            a[tn], b, acc[si][tn], 0, 0, 0);
                }
            }
        }
        __syncthreads();
    }

    #pragma unroll
    for (int si = 0; si < S; ++si) {
        int oh = oh0 + dy[si], ow = ow0 + dx[si];
        #pragma unroll
        for (int tn = 0; tn < NT; ++tn) {
            int co_b = co0 + tn*16 + q*4;
            ushort4 st;
            #pragma unroll
            for (int r = 0; r < 4; ++r) {
                float v = acc[si][tn][r] + Be[e*CO + co_b + r];
                v = fmaxf(v, 0.f);
                ((unsigned short*)&st)[r] = f2bf(v);
            }
            *reinterpret_cast<ushort4*>(&out[(((long)n*HO + oh)*HO + ow)*CO + co_b]) = st;
        }
    }
}

// ===================== 1x1 head: NHWC bf16 -> NCHW fp32 ====================
__global__ __launch_bounds__(256) void head_kernel(const unsigned short* __restrict__ d5,
                                                   const float* __restrict__ Wh,
                                                   const float* __restrict__ bh,
                                                   const int* __restrict__ cls_i,
                                                   float* __restrict__ seg)
{
    int n = blockIdx.y;
    int p = blockIdx.x*256 + threadIdx.x;
    __shared__ float w[85];
    int e = cls_i[n];
    if (threadIdx.x < 80) w[threadIdx.x] = Wh[(long)e*80 + threadIdx.x];
    if (threadIdx.x < 5)  w[80+threadIdx.x] = bh[e*5 + threadIdx.x];
    __syncthreads();
    const unsigned short* dp = d5 + ((long)n*16384 + p)*16;
    uint4 u0 = *reinterpret_cast<const uint4*>(dp);
    uint4 u1 = *reinterpret_cast<const uint4*>(dp + 8);
    float x[16];
    unsigned int uu[4] = {u0.x, u0.y, u0.z, u0.w};
    unsigned int vv[4] = {u1.x, u1.y, u1.z, u1.w};
    #pragma unroll
    for (int i = 0; i < 4; ++i) {
        x[2*i+0] = __uint_as_float(uu[i] << 16);
        x[2*i+1] = __uint_as_float(uu[i] & 0xffff0000u);
        x[8+2*i+0] = __uint_as_float(vv[i] << 16);
        x[8+2*i+1] = __uint_as_float(vv[i] & 0xffff0000u);
    }
    #pragma unroll
    for (int co = 0; co < 5; ++co) {
        float sacc = w[80+co];
        #pragma unroll
        for (int ci = 0; ci < 16; ++ci) sacc += x[ci]*w[co*16+ci];
        seg[((long)n*5 + co)*16384 + p] = sacc;
    }
}

// ===========================================================================
extern "C" void kernel_launch(void* const* d_in, const int* in_sizes, int n_in,
                              void* d_out, int out_size, void* d_ws, size_t ws_size,
                              hipStream_t stream)
{
    const float* x   = (const float*)d_in[0];
    const float* Wb1 = (const float*)d_in[1];  const float* bb1 = (const float*)d_in[2];
    const float* Wb2 = (const float*)d_in[3];  const float* bb2 = (const float*)d_in[4];
    const float* Wb3 = (const float*)d_in[5];  const float* bb3 = (const float*)d_in[6];
    const float* Wb4 = (const float*)d_in[7];  const float* bb4 = (const float*)d_in[8];
    const float* Wb5 = (const float*)d_in[9];  const float* bb5 = (const float*)d_in[10];
    const float* Wc1 = (const float*)d_in[11]; const float* bc1 = (const float*)d_in[12];
    const float* Wc2 = (const float*)d_in[13]; const float* bc2 = (const float*)d_in[14];
    const float* We1 = (const float*)d_in[15]; const float* be1 = (const float*)d_in[16];
    const float* We2 = (const float*)d_in[17]; const float* be2 = (const float*)d_in[18];
    const float* We3 = (const float*)d_in[19]; const float* be3 = (const float*)d_in[20];
    const float* We4 = (const float*)d_in[21]; const float* be4 = (const float*)d_in[22];
    const float* We5 = (const float*)d_in[23]; const float* be5 = (const float*)d_in[24];
    const float* We6 = (const float*)d_in[25]; const float* be6 = (const float*)d_in[26];

    float* out = (float*)d_out;
    char* ws = (char*)d_ws;

    // ---- X region (67 MB): H1 -> {H3, WB4/5} -> {P, Q, WT1-5} ----
    unsigned short* H1hi = (unsigned short*)(ws + 0);          // 33,554,432 B
    unsigned short* H1lo = (unsigned short*)(ws + 33554432);
    unsigned short* H3hi = (unsigned short*)(ws + 0);          //  8,388,608 B
    unsigned short* H3lo = (unsigned short*)(ws + 8388608);
    unsigned short* WB4hi = (unsigned short*)(ws + 16777216);  //  2,359,296 B
    unsigned short* WB4lo = (unsigned short*)(ws + 19136512);
    unsigned short* WB5hi = (unsigned short*)(ws + 21495808);  //  4,718,592 B
    unsigned short* WB5lo = (unsigned short*)(ws + 26214400);
    unsigned short* P    = (unsigned short*)(ws + 0);          // 33,554,432 B
    unsigned short* Q    = (unsigned short*)(ws + 33554432);   // 16,777,216 B
    unsigned short* WT1  = (unsigned short*)(ws + 50331648);   // 11,796,480 B
    unsigned short* WT2  = (unsigned short*)(ws + 62128128);   //  2,949,120 B
    unsigned short* WT3  = (unsigned short*)(ws + 65077248);   //    737,280 B
    unsigned short* WT4  = (unsigned short*)(ws + 65814528);   //    184,320 B
    unsigned short* WT5  = (unsigned short*)(ws + 65998848);   //     46,080 B

    // ---- Y region (33.5 MB): H2 -> {H4, FEATS, pooled/hidden/cls} ----
    char* Y = ws + 67108864;
    unsigned short* H2hi = (unsigned short*)(Y + 0);           // 16,777,216 B
    unsigned short* H2lo = (unsigned short*)(Y + 16777216);
    unsigned short* H4hi = (unsigned short*)(Y + 0);           //  4,194,304 B
    unsigned short* H4lo = (unsigned short*)(Y + 4194304);
    unsigned short* FShi = (unsigned short*)(Y + 8388608);     //  1,048,576 B
    unsigned short* FSlo = (unsigned short*)(Y + 9437184);
    float* pooled = (float*)(Y + 10485760);                    //    131,072 B
    float* hidden = (float*)(Y + 10616832);                    //     32,768 B
    int*   cls_i  = (int*)(Y + 10649600);

    // ---- W23 tail (1.5 MB) ----
    char* W23 = ws + 100663296;
    unsigned short* WB2hi = (unsigned short*)(W23 + 0);        // 147,456 B
    unsigned short* WB2lo = (unsigned short*)(W23 + 147456);
    unsigned short* WB3hi = (unsigned short*)(W23 + 294912);   // 589,824 B
    unsigned short* WB3lo = (unsigned short*)(W23 + 884736);

    // ---- backbone weight transposes (conv2/3 only; 4/5 after conv2) ----
    hipLaunchKernelGGL((wtrans_split_kernel<64>),  dim3(128), dim3(256), 0, stream, Wb2, WB2hi, WB2lo);
    hipLaunchKernelGGL((wtrans_split_kernel<128>), dim3(256), dim3(256), 0, stream, Wb3, WB3hi, WB3lo);

    // ---- conv1 (fp32 direct, split output) ----
    hipLaunchKernelGGL(conv1_kernel, dim3(64,2,64), dim3(256), 0, stream, x, Wb1, bb1, H1hi, H1lo);

    // ---- conv2 ----
    hipLaunchKernelGGL((bb_conv_s2<64,128,32,8,8,4>), dim3(16,2,64), dim3(256), 0, stream,
                       H1hi, H1lo, WB2hi, WB2lo, bb2, H2hi, H2lo);

    // ---- H1 dead: transpose conv4/5 + decoder weights into X ----
    hipLaunchKernelGGL((wtrans_split_kernel<256>), dim3(512), dim3(256), 0, stream, Wb4, WB4hi, WB4lo);
    hipLaunchKernelGGL((wtrans_split_kernel<512>), dim3(512), dim3(256), 0, stream, Wb5, WB5hi, WB5lo);
    hipLaunchKernelGGL((wtrans_kernel<512>), dim3(5*256), dim3(256), 0, stream, We1, WT1);
    hipLaunchKernelGGL((wtrans_kernel<256>), dim3(5*128), dim3(256), 0, stream, We2, WT2);
    hipLaunchKernelGGL((wtrans_kernel<128>), dim3(5*64),  dim3(256), 0, stream, We3, WT3);
    hipLaunchKernelGGL((wtrans_kernel<64>),  dim3(5*32),  dim3(256), 0, stream, We4, WT4);
    hipLaunchKernelGGL((wtrans_kernel<32>),  dim3(5*16),  dim3(256), 0, stream, We5, WT5);

    // ---- conv3..5 ----
    hipLaunchKernelGGL((bb_conv_s2<128,256,16,8,8,4>), dim3(4,4,64), dim3(256), 0, stream,
                       H2hi, H2lo, WB3hi, WB3lo, bb3, H3hi, H3lo);
    hipLaunchKernelGGL((bb_conv_s2<256,512, 8,8,8,4>), dim3(1,8,64), dim3(256), 0, stream,
                       H3hi, H3lo, WB4hi, WB4lo, bb4, H4hi, H4lo);
    hipLaunchKernelGGL((bb_conv_s2<512,512, 4,4,4,2>), dim3(1,4,64), dim3(256), 0, stream,
                       H4hi, H4lo, WB5hi, WB5lo, bb5, FShi, FSlo);

    // ---- classifier ----
    hipLaunchKernelGGL(pool_kernel, dim3(128), dim3(256), 0, stream, FShi, FSlo, pooled);
    hipLaunchKernelGGL(fc1_kernel,  dim3(32),  dim3(256), 0, stream, pooled, Wc1, bc1, hidden);
    hipLaunchKernelGGL(fc2_kernel,  dim3(64),  dim3(64),  0, stream, hidden, Wc2, bc2, out, cls_i);

    // ---- decoder: FShi -> P -> Q -> P -> Q -> P ----
    hipLaunchKernelGGL((dec_conv_kernel<512,256,  8,  8, 8, 64,64>), dim3(1,  4,64), dim3(256), 0, stream, FShi, WT1, be1, cls_i, P);
    hipLaunchKernelGGL((dec_conv_kernel<256,128, 16,  8, 8, 64,64>), dim3(4,  2,64), dim3(256), 0, stream, P,    WT2, be2, cls_i, Q);
    hipLaunchKernelGGL((dec_conv_kernel<128, 64, 32,  8, 8, 64,64>), dim3(16, 1,64), dim3(256), 0, stream, Q,    WT3, be3, cls_i, P);
    hipLaunchKernelGGL((dec_conv_kernel< 64, 32, 64, 16,16, 32,64>), dim3(16, 1,64), dim3(256), 0, stream, P,    WT4, be4, cls_i, Q);
    hipLaunchKernelGGL((dec_conv_kernel< 32, 16,128, 16,16, 16,32>), dim3(64, 1,64), dim3(256), 0, stream, Q,    WT5, be5, cls_i, P);

    // ---- 1x1 head -> seg (NCHW fp32) ----
    hipLaunchKernelGGL(head_kernel, dim3(64,64), dim3(256), 0, stream, P, We6, be6, cls_i, out + 384);
}

// Round 4
// 1027.346 us; speedup vs baseline: 2.7193x; 1.0916x over previous
//
#include <hip/hip_runtime.h>
#include <hip/hip_bf16.h>

// ---------------------------------------------------------------------------
// R4: R3 + 3-tap-deep register prefetch of weight fragments in both the
// split-bf16 backbone conv and the bf16 decoder conv (kills the per-tap
// global-load stall that held MfmaUtil at 6%).
// ---------------------------------------------------------------------------

typedef __attribute__((ext_vector_type(8))) short bf16x8;   // 8 bf16 = 4 VGPRs
typedef __attribute__((ext_vector_type(4))) float f32x4;

static __device__ __forceinline__ unsigned short f2bf(float f) {
    __hip_bfloat16 h = __float2bfloat16(f);
    return *reinterpret_cast<unsigned short*>(&h);
}
static __device__ __forceinline__ float bf2f(unsigned short u) {
    return __uint_as_float(((unsigned int)u) << 16);
}

// ===================== conv1: fp32 direct, split NHWC output ===============
__global__ __launch_bounds__(256)
void conv1_kernel(const float* __restrict__ in, const float* __restrict__ W,
                  const float* __restrict__ Bias,
                  unsigned short* __restrict__ out_hi,
                  unsigned short* __restrict__ out_lo)
{
    constexpr int R = 17, C = 17;
    __shared__ float ilds[3*R*C];
    __shared__ float wlds[27*32];
    const int n = blockIdx.z, co0 = blockIdx.y*32;
    const int ty = blockIdx.x >> 3, tx = blockIdx.x & 7;
    const int oh0 = ty*8, ow0 = tx*8;
    const int t = threadIdx.x, p = t & 63, grp = t >> 6;
    const int py = p >> 3, px = p & 7;
    const int r0 = 2*oh0, c0 = 2*ow0;

    const float* ibase = in + (long)n*3*16384;
    for (int idx = t; idx < 3*R*C; idx += 256) {
        int ck = idx/(R*C), rc = idx%(R*C);
        int r = rc/C, c = rc%C;
        int ih = r0+r, iw = c0+c;
        float v = 0.f;
        if (ih < 128 && iw < 128) v = ibase[ck*16384 + ih*128 + iw];
        ilds[idx] = v;
    }
    for (int idx = t; idx < 32*27; idx += 256) {
        int co = idx & 31, rem = idx >> 5;
        wlds[rem*32 + co] = W[(co0+co)*27 + rem];
    }
    __syncthreads();

    float acc[8];
    #pragma unroll
    for (int i=0;i<8;i++) acc[i]=0.f;

    #pragma unroll
    for (int ck = 0; ck < 3; ++ck) {
        float xv[9];
        #pragma unroll
        for (int kh = 0; kh < 3; ++kh)
            #pragma unroll
            for (int kw = 0; kw < 3; ++kw)
                xv[kh*3+kw] = ilds[ck*289 + (2*py+kh)*17 + 2*px+kw];
        #pragma unroll
        for (int k = 0; k < 9; ++k) {
            #pragma unroll
            for (int g = 0; g < 2; ++g) {
                const float4 w = *reinterpret_cast<const float4*>(
                    &wlds[(ck*9+k)*32 + grp*8 + g*4]);
                acc[g*4+0] += xv[k]*w.x;
                acc[g*4+1] += xv[k]*w.y;
                acc[g*4+2] += xv[k]*w.z;
                acc[g*4+3] += xv[k]*w.w;
            }
        }
    }

    const long obase = (((long)n*64 + oh0+py)*64 + ow0+px)*64 + co0 + grp*8;
    #pragma unroll
    for (int g = 0; g < 2; ++g) {
        ushort4 sh, sl;
        #pragma unroll
        for (int j = 0; j < 4; ++j) {
            int co = co0 + grp*8 + g*4 + j;
            float v = fmaxf(acc[g*4+j] + Bias[co], 0.f);
            unsigned short h = f2bf(v);
            ((unsigned short*)&sh)[j] = h;
            ((unsigned short*)&sl)[j] = f2bf(v - bf2f(h));
        }
        *reinterpret_cast<ushort4*>(&out_hi[obase + g*4]) = sh;
        *reinterpret_cast<ushort4*>(&out_lo[obase + g*4]) = sl;
    }
}

// ===================== split-bf16 MFMA stride-2 conv (backbone 2-5) ========
template<int CI,int CO,int HO,int TH,int TW,int NT>
__global__ __launch_bounds__(256, 2)
void bb_conv_s2(const unsigned short* __restrict__ in_hi,
                const unsigned short* __restrict__ in_lo,
                const unsigned short* __restrict__ Whi,
                const unsigned short* __restrict__ Wlo,
                const float* __restrict__ Bias,
                unsigned short* __restrict__ out_hi,
                unsigned short* __restrict__ out_lo)
{
    constexpr int HI = HO*2;
    constexpr int R = 2*TH+1, C = 2*TW+1;
    constexpr int CK = 32;
    constexpr int PITCH = CK + 8;
    constexpr int NSUB = (TH*TW)/16;
    constexpr int SUBW = (TW>=8)?8:TW;
    constexpr int COG  = 4/NSUB;
    constexpr int CO_T = COG*NT*16;
    constexpr int SUBH = 16/SUBW;
    static_assert(NSUB==1 || NSUB==4, "tile is 16 or 64 px");

    __shared__ __align__(16) unsigned short hi_lds[R*C*PITCH];
    __shared__ __align__(16) unsigned short lo_lds[R*C*PITCH];

    const int n   = blockIdx.z;
    const int co0 = blockIdx.y * CO_T;
    constexpr int TILES_X = HO/TW;
    const int ty = blockIdx.x / TILES_X, tx = blockIdx.x % TILES_X;
    const int oh0 = ty*TH, ow0 = tx*TW;
    const int r0 = 2*oh0, c0 = 2*ow0;

    const int t = threadIdx.x;
    const int w = t >> 6, lane = t & 63;
    const int s = lane & 15, q = lane >> 4;
    const int sub = w % NSUB, cog = w / NSUB;
    const int dy = sub*SUBH + s/SUBW;
    const int dx = s % SUBW;

    const unsigned short* inHn = in_hi + (long)n*HI*HI*CI;
    const unsigned short* inLn = in_lo + (long)n*HI*HI*CI;

    int wrow[NT];
    #pragma unroll
    for (int tn = 0; tn < NT; ++tn)
        wrow[tn] = (co0 + cog*NT*16 + tn*16 + s)*9*CI + q*8;

    f32x4 acc[NT];
    #pragma unroll
    for (int tn = 0; tn < NT; ++tn) acc[tn] = (f32x4){0.f,0.f,0.f,0.f};

    for (int ci0 = 0; ci0 < CI; ci0 += CK) {
        // ---- stage hi & lo input tiles (uint4 = 8 bf16), zero-padded ----
        constexpr int C8 = CK/8;
        for (int i8 = t; i8 < R*C*C8; i8 += 256) {
            int pix = i8 / C8, cs = i8 % C8;
            int r = pix / C, c = pix % C;
            int ih = r0 + r, iw = c0 + c;
            uint4 vh = {0u,0u,0u,0u}, vl = {0u,0u,0u,0u};
            if (ih < HI && iw < HI) {
                long off = ((long)ih*HI + iw)*CI + ci0 + cs*8;
                vh = *reinterpret_cast<const uint4*>(&inHn[off]);
                vl = *reinterpret_cast<const uint4*>(&inLn[off]);
            }
            *reinterpret_cast<uint4*>(&hi_lds[pix*PITCH + cs*8]) = vh;
            *reinterpret_cast<uint4*>(&lo_lds[pix*PITCH + cs*8]) = vl;
        }
        __syncthreads();

        // ---- 3-tap-deep register prefetch pipeline over the 9 taps ----
        bf16x8 wh[9][NT], wl[9][NT];
        #pragma unroll
        for (int pf = 0; pf < 3; ++pf)
            #pragma unroll
            for (int tn = 0; tn < NT; ++tn) {
                const int wo = wrow[tn] + pf*CI + ci0;
                wh[pf][tn] = *reinterpret_cast<const bf16x8*>(&Whi[wo]);
                wl[pf][tn] = *reinterpret_cast<const bf16x8*>(&Wlo[wo]);
            }
        #pragma unroll
        for (int k = 0; k < 9; ++k) {
            if (k + 3 < 9) {
                #pragma unroll
                for (int tn = 0; tn < NT; ++tn) {
                    const int wo = wrow[tn] + (k+3)*CI + ci0;
                    wh[k+3][tn] = *reinterpret_cast<const bf16x8*>(&Whi[wo]);
                    wl[k+3][tn] = *reinterpret_cast<const bf16x8*>(&Wlo[wo]);
                }
            }
            const int kh = k/3, kw = k%3;
            const int pi = (2*dy + kh)*C + 2*dx + kw;
            bf16x8 bh = *reinterpret_cast<const bf16x8*>(&hi_lds[pi*PITCH + q*8]);
            bf16x8 bl = *reinterpret_cast<const bf16x8*>(&lo_lds[pi*PITCH + q*8]);
            #pragma unroll
            for (int tn = 0; tn < NT; ++tn) {
                acc[tn] = __builtin_amdgcn_mfma_f32_16x16x32_bf16(wh[k][tn], bh, acc[tn], 0,0,0);
                acc[tn] = __builtin_amdgcn_mfma_f32_16x16x32_bf16(wh[k][tn], bl, acc[tn], 0,0,0);
                acc[tn] = __builtin_amdgcn_mfma_f32_16x16x32_bf16(wl[k][tn], bh, acc[tn], 0,0,0);
            }
        }
        __syncthreads();
    }

    const int oh = oh0 + dy, ow = ow0 + dx;
    #pragma unroll
    for (int tn = 0; tn < NT; ++tn) {
        int co_b = co0 + cog*NT*16 + tn*16 + q*4;
        ushort4 sh, sl;
        #pragma unroll
        for (int r = 0; r < 4; ++r) {
            float v = fmaxf(acc[tn][r] + Bias[co_b + r], 0.f);
            unsigned short h = f2bf(v);
            ((unsigned short*)&sh)[r] = h;
            ((unsigned short*)&sl)[r] = f2bf(v - bf2f(h));
        }
        long ob = (((long)n*HO + oh)*HO + ow)*CO + co_b;
        *reinterpret_cast<ushort4*>(&out_hi[ob]) = sh;
        *reinterpret_cast<ushort4*>(&out_lo[ob]) = sl;
    }
}

// ===================== weight transforms ===================================
template<int CI>
__global__ __launch_bounds__(256)
void wtrans_split_kernel(const float* __restrict__ src,
                         unsigned short* __restrict__ hi,
                         unsigned short* __restrict__ lo)
{
    __shared__ float buf[CI*9];
    const long blk = blockIdx.x;
    const float* sp = src + blk*(CI*9);
    for (int i = threadIdx.x; i < CI*9; i += 256) buf[i] = sp[i];
    __syncthreads();
    for (int i = threadIdx.x; i < CI*9; i += 256) {
        int k = i / CI, ci = i % CI;
        float v = buf[ci*9 + k];
        unsigned short h = f2bf(v);
        hi[blk*(CI*9) + i] = h;
        lo[blk*(CI*9) + i] = f2bf(v - bf2f(h));
    }
}

template<int CI>
__global__ __launch_bounds__(256)
void wtrans_kernel(const float* __restrict__ src, unsigned short* __restrict__ dst)
{
    __shared__ float buf[CI*9];
    const long blk = blockIdx.x;
    const float* sp = src + blk*(CI*9);
    for (int i = threadIdx.x; i < CI*9; i += 256) buf[i] = sp[i];
    __syncthreads();
    unsigned short* d = dst + blk*(CI*9);
    for (int i = threadIdx.x; i < CI*9; i += 256) {
        int k = i / CI, ci = i % CI;
        d[i] = f2bf(buf[ci*9 + k]);
    }
}

// ===================== classifier path =====================================
__global__ __launch_bounds__(256) void pool_kernel(const unsigned short* __restrict__ fh,
                                                   const unsigned short* __restrict__ fl,
                                                   float* __restrict__ pooled)
{
    int i = blockIdx.x*256 + threadIdx.x;
    if (i < 64*512) {
        int n = i >> 9, ci = i & 511;
        const unsigned short* ph = fh + (long)n*8192 + ci;
        const unsigned short* pl = fl + (long)n*8192 + ci;
        float sacc = 0.f;
        #pragma unroll
        for (int px = 0; px < 16; ++px)
            sacc += bf2f(ph[px*512]) + bf2f(pl[px*512]);
        pooled[i] = sacc * (1.f/16.f);
    }
}

__global__ __launch_bounds__(256) void fc1_kernel(const float* __restrict__ pooled,
                                                  const float* __restrict__ Wc1,
                                                  const float* __restrict__ bc1,
                                                  float* __restrict__ hidden)
{
    int i = blockIdx.x*256 + threadIdx.x;
    if (i < 64*128) {
        int n = i/128, j = i%128;
        const float* p = pooled + n*512;
        const float* w = Wc1 + j*512;
        float sacc = 0.f;
        for (int k = 0; k < 512; ++k) sacc += p[k]*w[k];
        hidden[i] = fmaxf(sacc + bc1[j], 0.f);
    }
}

__global__ __launch_bounds__(64) void fc2_kernel(const float* __restrict__ hidden,
                                                 const float* __restrict__ Wc2,
                                                 const float* __restrict__ bc2,
                                                 float* __restrict__ out,
                                                 int* __restrict__ cls_i)
{
    int n = blockIdx.x;
    int j = threadIdx.x;
    __shared__ float lg[5];
    if (j < 5) {
        const float* h = hidden + n*128;
        const float* w = Wc2 + j*128;
        float sacc = 0.f;
        for (int k = 0; k < 128; ++k) sacc += h[k]*w[k];
        sacc += bc2[j];
        out[n*5 + j] = sacc;
        lg[j] = sacc;
    }
    __syncthreads();
    if (j == 0) {
        int am = 0; float best = lg[0];
        #pragma unroll
        for (int k = 1; k < 5; ++k) if (lg[k] > best) { best = lg[k]; am = k; }
        out[320 + n] = (float)am;
        cls_i[n] = am;
    }
}

// ===================== bf16 MFMA decoder conv ==============================
template<int CI,int CO,int HO,int TH,int TW,int CO_T,int CK>
__global__ __launch_bounds__(256, 2)
void dec_conv_kernel(const unsigned short* __restrict__ in,
                     const unsigned short* __restrict__ WT,
                     const float* __restrict__ Be,
                     const int* __restrict__ cls_i,
                     unsigned short* __restrict__ out)
{
    constexpr int HI = HO/2;
    constexpr int R = TH/2 + 2, C = TW/2 + 2;
    constexpr int PITCH = CK + 8;
    constexpr int NT = CO_T/16;
    constexpr int S  = (TH*TW)/64;
    constexpr int SXT = TW/8;
    constexpr int CKQ = CK/32;
    constexpr int NST = 9*CKQ;
    constexpr int PF  = 3;

    __shared__ __align__(16) unsigned short ilds[R*C*PITCH];

    const int n = blockIdx.z;
    const int e = cls_i[n];
    const int co0 = blockIdx.y * CO_T;
    constexpr int TILES_X = HO/TW;
    const int ty = blockIdx.x / TILES_X, tx = blockIdx.x % TILES_X;
    const int oh0 = ty*TH, ow0 = tx*TW;
    const int ih0 = oh0/2 - 1, iw0 = ow0/2 - 1;

    const int t = threadIdx.x;
    const int w = t >> 6;
    const int lane = t & 63;
    const int s = lane & 15;
    const int q = lane >> 4;

    const unsigned short* Wbase = WT + ((long)e*CO + co0)*9*CI;
    const unsigned short* inN   = in + (long)n*HI*HI*CI;

    int wrow[NT];
    #pragma unroll
    for (int tn = 0; tn < NT; ++tn)
        wrow[tn] = (tn*16 + s)*9*CI + q*8;

    f32x4 acc[S][NT];
    #pragma unroll
    for (int si = 0; si < S; ++si)
        #pragma unroll
        for (int tn = 0; tn < NT; ++tn)
            acc[si][tn] = (f32x4){0.f,0.f,0.f,0.f};

    int dy[S], dx[S];
    #pragma unroll
    for (int si = 0; si < S; ++si) {
        int sub = w + si*4;
        int sy = sub / SXT, sx = sub % SXT;
        dy[si] = sy*2 + (s >> 3);
        dx[si] = sx*8 + (s & 7);
    }

    for (int ci0 = 0; ci0 < CI; ci0 += CK) {
        constexpr int C8 = CK/8;
        for (int i8 = t; i8 < R*C*C8; i8 += 256) {
            int pix = i8 / C8, cs = i8 % C8;
            int r = pix / C, c = pix % C;
            int ih = ih0 + r, iw = iw0 + c;
            uint4 v = {0u,0u,0u,0u};
            if (ih >= 0 && ih < HI && iw >= 0 && iw < HI)
                v = *reinterpret_cast<const uint4*>(&inN[((long)ih*HI + iw)*CI + ci0 + cs*8]);
            *reinterpret_cast<uint4*>(&ilds[pix*PITCH + cs*8]) = v;
        }
        __syncthreads();

        // ---- register prefetch pipeline over (tap, ci-quad) steps ----
        bf16x8 a[NST][NT];
        #pragma unroll
        for (int pf = 0; pf < PF && pf < NST; ++pf)
            #pragma unroll
            for (int tn = 0; tn < NT; ++tn) {
                const int k = pf/CKQ, ckq = pf%CKQ;
                a[pf][tn] = *reinterpret_cast<const bf16x8*>(
                    &Wbase[wrow[tn] + k*CI + ci0 + ckq*32]);
            }
        #pragma unroll
        for (int st = 0; st < NST; ++st) {
            if (st + PF < NST) {
                const int kp = (st+PF)/CKQ, cp = (st+PF)%CKQ;
                #pragma unroll
                for (int tn = 0; tn < NT; ++tn)
                    a[st+PF][tn] = *reinterpret_cast<const bf16x8*>(
                        &Wbase[wrow[tn] + kp*CI + ci0 + cp*32]);
            }
            const int k = st/CKQ, ckq = st%CKQ;
            const int kh = k/3, kw = k%3;
            #pragma unroll
            for (int si = 0; si < S; ++si) {
                int ihr = ((dy[si] + kh - 1) >> 1) + 1;
                int iwr = ((dx[si] + kw - 1) >> 1) + 1;
                bf16x8 b = *reinterpret_cast<const bf16x8*>(
                    &ilds[(ihr*C + iwr)*PITCH + ckq*32 + q*8]);
                #pragma unroll
                for (int tn = 0; tn < NT; ++tn)
                    acc[si][tn] = __builtin_amdgcn_mfma_f32_16x16x32_bf16(
                        a[st][tn], b, acc[si][tn], 0, 0, 0);
            }
        }
        __syncthreads();
    }

    #pragma unroll
    for (int si = 0; si < S; ++si) {
        int oh = oh0 + dy[si], ow = ow0 + dx[si];
        #pragma unroll
        for (int tn = 0; tn < NT; ++tn) {
            int co_b = co0 + tn*16 + q*4;
            ushort4 st4;
            #pragma unroll
            for (int r = 0; r < 4; ++r) {
                float v = acc[si][tn][r] + Be[e*CO + co_b + r];
                v = fmaxf(v, 0.f);
                ((unsigned short*)&st4)[r] = f2bf(v);
            }
            *reinterpret_cast<ushort4*>(&out[(((long)n*HO + oh)*HO + ow)*CO + co_b]) = st4;
        }
    }
}

// ===================== 1x1 head: NHWC bf16 -> NCHW fp32 ====================
__global__ __launch_bounds__(256) void head_kernel(const unsigned short* __restrict__ d5,
                                                   const float* __restrict__ Wh,
                                                   const float* __restrict__ bh,
                                                   const int* __restrict__ cls_i,
                                                   float* __restrict__ seg)
{
    int n = blockIdx.y;
    int p = blockIdx.x*256 + threadIdx.x;
    __shared__ float w[85];
    int e = cls_i[n];
    if (threadIdx.x < 80) w[threadIdx.x] = Wh[(long)e*80 + threadIdx.x];
    if (threadIdx.x < 5)  w[80+threadIdx.x] = bh[e*5 + threadIdx.x];
    __syncthreads();
    const unsigned short* dp = d5 + ((long)n*16384 + p)*16;
    uint4 u0 = *reinterpret_cast<const uint4*>(dp);
    uint4 u1 = *reinterpret_cast<const uint4*>(dp + 8);
    float x[16];
    unsigned int uu[4] = {u0.x, u0.y, u0.z, u0.w};
    unsigned int vv[4] = {u1.x, u1.y, u1.z, u1.w};
    #pragma unroll
    for (int i = 0; i < 4; ++i) {
        x[2*i+0] = __uint_as_float(uu[i] << 16);
        x[2*i+1] = __uint_as_float(uu[i] & 0xffff0000u);
        x[8+2*i+0] = __uint_as_float(vv[i] << 16);
        x[8+2*i+1] = __uint_as_float(vv[i] & 0xffff0000u);
    }
    #pragma unroll
    for (int co = 0; co < 5; ++co) {
        float sacc = w[80+co];
        #pragma unroll
        for (int ci = 0; ci < 16; ++ci) sacc += x[ci]*w[co*16+ci];
        seg[((long)n*5 + co)*16384 + p] = sacc;
    }
}

// ===========================================================================
extern "C" void kernel_launch(void* const* d_in, const int* in_sizes, int n_in,
                              void* d_out, int out_size, void* d_ws, size_t ws_size,
                              hipStream_t stream)
{
    const float* x   = (const float*)d_in[0];
    const float* Wb1 = (const float*)d_in[1];  const float* bb1 = (const float*)d_in[2];
    const float* Wb2 = (const float*)d_in[3];  const float* bb2 = (const float*)d_in[4];
    const float* Wb3 = (const float*)d_in[5];  const float* bb3 = (const float*)d_in[6];
    const float* Wb4 = (const float*)d_in[7];  const float* bb4 = (const float*)d_in[8];
    const float* Wb5 = (const float*)d_in[9];  const float* bb5 = (const float*)d_in[10];
    const float* Wc1 = (const float*)d_in[11]; const float* bc1 = (const float*)d_in[12];
    const float* Wc2 = (const float*)d_in[13]; const float* bc2 = (const float*)d_in[14];
    const float* We1 = (const float*)d_in[15]; const float* be1 = (const float*)d_in[16];
    const float* We2 = (const float*)d_in[17]; const float* be2 = (const float*)d_in[18];
    const float* We3 = (const float*)d_in[19]; const float* be3 = (const float*)d_in[20];
    const float* We4 = (const float*)d_in[21]; const float* be4 = (const float*)d_in[22];
    const float* We5 = (const float*)d_in[23]; const float* be5 = (const float*)d_in[24];
    const float* We6 = (const float*)d_in[25]; const float* be6 = (const float*)d_in[26];

    float* out = (float*)d_out;
    char* ws = (char*)d_ws;

    // ---- X region (67 MB): H1 -> {H3, WB4/5} -> {P, Q, WT1-5} ----
    unsigned short* H1hi = (unsigned short*)(ws + 0);
    unsigned short* H1lo = (unsigned short*)(ws + 33554432);
    unsigned short* H3hi = (unsigned short*)(ws + 0);
    unsigned short* H3lo = (unsigned short*)(ws + 8388608);
    unsigned short* WB4hi = (unsigned short*)(ws + 16777216);
    unsigned short* WB4lo = (unsigned short*)(ws + 19136512);
    unsigned short* WB5hi = (unsigned short*)(ws + 21495808);
    unsigned short* WB5lo = (unsigned short*)(ws + 26214400);
    unsigned short* P    = (unsigned short*)(ws + 0);
    unsigned short* Q    = (unsigned short*)(ws + 33554432);
    unsigned short* WT1  = (unsigned short*)(ws + 50331648);
    unsigned short* WT2  = (unsigned short*)(ws + 62128128);
    unsigned short* WT3  = (unsigned short*)(ws + 65077248);
    unsigned short* WT4  = (unsigned short*)(ws + 65814528);
    unsigned short* WT5  = (unsigned short*)(ws + 65998848);

    // ---- Y region (33.5 MB): H2 -> {H4, FEATS, pooled/hidden/cls} ----
    char* Y = ws + 67108864;
    unsigned short* H2hi = (unsigned short*)(Y + 0);
    unsigned short* H2lo = (unsigned short*)(Y + 16777216);
    unsigned short* H4hi = (unsigned short*)(Y + 0);
    unsigned short* H4lo = (unsigned short*)(Y + 4194304);
    unsigned short* FShi = (unsigned short*)(Y + 8388608);
    unsigned short* FSlo = (unsigned short*)(Y + 9437184);
    float* pooled = (float*)(Y + 10485760);
    float* hidden = (float*)(Y + 10616832);
    int*   cls_i  = (int*)(Y + 10649600);

    // ---- W23 tail (1.5 MB) ----
    char* W23 = ws + 100663296;
    unsigned short* WB2hi = (unsigned short*)(W23 + 0);
    unsigned short* WB2lo = (unsigned short*)(W23 + 147456);
    unsigned short* WB3hi = (unsigned short*)(W23 + 294912);
    unsigned short* WB3lo = (unsigned short*)(W23 + 884736);

    // ---- backbone weight transposes (conv2/3 only; 4/5 after conv2) ----
    hipLaunchKernelGGL((wtrans_split_kernel<64>),  dim3(128), dim3(256), 0, stream, Wb2, WB2hi, WB2lo);
    hipLaunchKernelGGL((wtrans_split_kernel<128>), dim3(256), dim3(256), 0, stream, Wb3, WB3hi, WB3lo);

    // ---- conv1 (fp32 direct, split output) ----
    hipLaunchKernelGGL(conv1_kernel, dim3(64,2,64), dim3(256), 0, stream, x, Wb1, bb1, H1hi, H1lo);

    // ---- conv2 ----
    hipLaunchKernelGGL((bb_conv_s2<64,128,32,8,8,4>), dim3(16,2,64), dim3(256), 0, stream,
                       H1hi, H1lo, WB2hi, WB2lo, bb2, H2hi, H2lo);

    // ---- H1 dead: transpose conv4/5 + decoder weights into X ----
    hipLaunchKernelGGL((wtrans_split_kernel<256>), dim3(512), dim3(256), 0, stream, Wb4, WB4hi, WB4lo);
    hipLaunchKernelGGL((wtrans_split_kernel<512>), dim3(512), dim3(256), 0, stream, Wb5, WB5hi, WB5lo);
    hipLaunchKernelGGL((wtrans_kernel<512>), dim3(5*256), dim3(256), 0, stream, We1, WT1);
    hipLaunchKernelGGL((wtrans_kernel<256>), dim3(5*128), dim3(256), 0, stream, We2, WT2);
    hipLaunchKernelGGL((wtrans_kernel<128>), dim3(5*64),  dim3(256), 0, stream, We3, WT3);
    hipLaunchKernelGGL((wtrans_kernel<64>),  dim3(5*32),  dim3(256), 0, stream, We4, WT4);
    hipLaunchKernelGGL((wtrans_kernel<32>),  dim3(5*16),  dim3(256), 0, stream, We5, WT5);

    // ---- conv3..5 ----
    hipLaunchKernelGGL((bb_conv_s2<128,256,16,8,8,4>), dim3(4,4,64), dim3(256), 0, stream,
                       H2hi, H2lo, WB3hi, WB3lo, bb3, H3hi, H3lo);
    hipLaunchKernelGGL((bb_conv_s2<256,512, 8,8,8,4>), dim3(1,8,64), dim3(256), 0, stream,
                       H3hi, H3lo, WB4hi, WB4lo, bb4, H4hi, H4lo);
    hipLaunchKernelGGL((bb_conv_s2<512,512, 4,4,4,2>), dim3(1,4,64), dim3(256), 0, stream,
                       H4hi, H4lo, WB5hi, WB5lo, bb5, FShi, FSlo);

    // ---- classifier ----
    hipLaunchKernelGGL(pool_kernel, dim3(128), dim3(256), 0, stream, FShi, FSlo, pooled);
    hipLaunchKernelGGL(fc1_kernel,  dim3(32),  dim3(256), 0, stream, pooled, Wc1, bc1, hidden);
    hipLaunchKernelGGL(fc2_kernel,  dim3(64),  dim3(64),  0, stream, hidden, Wc2, bc2, out, cls_i);

    // ---- decoder: FShi -> P -> Q -> P -> Q -> P ----
    hipLaunchKernelGGL((dec_conv_kernel<512,256,  8,  8, 8, 64,64>), dim3(1,  4,64), dim3(256), 0, stream, FShi, WT1, be1, cls_i, P);
    hipLaunchKernelGGL((dec_conv_kernel<256,128, 16,  8, 8, 64,64>), dim3(4,  2,64), dim3(256), 0, stream, P,    WT2, be2, cls_i, Q);
    hipLaunchKernelGGL((dec_conv_kernel<128, 64, 32,  8, 8, 64,64>), dim3(16, 1,64), dim3(256), 0, stream, Q,    WT3, be3, cls_i, P);
    hipLaunchKernelGGL((dec_conv_kernel< 64, 32, 64, 16,16, 32,64>), dim3(16, 1,64), dim3(256), 0, stream, P,    WT4, be4, cls_i, Q);
    hipLaunchKernelGGL((dec_conv_kernel< 32, 16,128, 16,16, 16,32>), dim3(64, 1,64), dim3(256), 0, stream, Q,    WT5, be5, cls_i, P);

    // ---- 1x1 head -> seg (NCHW fp32) ----
    hipLaunchKernelGGL(head_kernel, dim3(64,64), dim3(256), 0, stream, P, We6, be6, cls_i, out + 384);
}

// Round 5
// 879.385 us; speedup vs baseline: 3.1768x; 1.1683x over previous
//
#include <hip/hip_runtime.h>
#include <hip/hip_bf16.h>

// ---------------------------------------------------------------------------
// R5: fat wave tiles (64co x 64px, NT=4 x S=4) for backbone conv2-5 and
// decoder dec1-3; 2-deep tap-pipelined global weight frags; waves split co.
// ---------------------------------------------------------------------------

typedef __attribute__((ext_vector_type(8))) short bf16x8;   // 8 bf16 = 4 VGPRs
typedef __attribute__((ext_vector_type(4))) float f32x4;

static __device__ __forceinline__ unsigned short f2bf(float f) {
    __hip_bfloat16 h = __float2bfloat16(f);
    return *reinterpret_cast<unsigned short*>(&h);
}
static __device__ __forceinline__ float bf2f(unsigned short u) {
    return __uint_as_float(((unsigned int)u) << 16);
}

// ===================== conv1: fp32 direct, split NHWC output ===============
__global__ __launch_bounds__(256)
void conv1_kernel(const float* __restrict__ in, const float* __restrict__ W,
                  const float* __restrict__ Bias,
                  unsigned short* __restrict__ out_hi,
                  unsigned short* __restrict__ out_lo)
{
    constexpr int R = 17, C = 17;
    __shared__ float ilds[3*R*C];
    __shared__ float wlds[27*32];
    const int n = blockIdx.z, co0 = blockIdx.y*32;
    const int ty = blockIdx.x >> 3, tx = blockIdx.x & 7;
    const int oh0 = ty*8, ow0 = tx*8;
    const int t = threadIdx.x, p = t & 63, grp = t >> 6;
    const int py = p >> 3, px = p & 7;
    const int r0 = 2*oh0, c0 = 2*ow0;

    const float* ibase = in + (long)n*3*16384;
    for (int idx = t; idx < 3*R*C; idx += 256) {
        int ck = idx/(R*C), rc = idx%(R*C);
        int r = rc/C, c = rc%C;
        int ih = r0+r, iw = c0+c;
        float v = 0.f;
        if (ih < 128 && iw < 128) v = ibase[ck*16384 + ih*128 + iw];
        ilds[idx] = v;
    }
    for (int idx = t; idx < 32*27; idx += 256) {
        int co = idx & 31, rem = idx >> 5;
        wlds[rem*32 + co] = W[(co0+co)*27 + rem];
    }
    __syncthreads();

    float acc[8];
    #pragma unroll
    for (int i=0;i<8;i++) acc[i]=0.f;

    #pragma unroll
    for (int ck = 0; ck < 3; ++ck) {
        float xv[9];
        #pragma unroll
        for (int kh = 0; kh < 3; ++kh)
            #pragma unroll
            for (int kw = 0; kw < 3; ++kw)
                xv[kh*3+kw] = ilds[ck*289 + (2*py+kh)*17 + 2*px+kw];
        #pragma unroll
        for (int k = 0; k < 9; ++k) {
            #pragma unroll
            for (int g = 0; g < 2; ++g) {
                const float4 w = *reinterpret_cast<const float4*>(
                    &wlds[(ck*9+k)*32 + grp*8 + g*4]);
                acc[g*4+0] += xv[k]*w.x;
                acc[g*4+1] += xv[k]*w.y;
                acc[g*4+2] += xv[k]*w.z;
                acc[g*4+3] += xv[k]*w.w;
            }
        }
    }

    const long obase = (((long)n*64 + oh0+py)*64 + ow0+px)*64 + co0 + grp*8;
    #pragma unroll
    for (int g = 0; g < 2; ++g) {
        ushort4 sh, sl;
        #pragma unroll
        for (int j = 0; j < 4; ++j) {
            int co = co0 + grp*8 + g*4 + j;
            float v = fmaxf(acc[g*4+j] + Bias[co], 0.f);
            unsigned short h = f2bf(v);
            ((unsigned short*)&sh)[j] = h;
            ((unsigned short*)&sl)[j] = f2bf(v - bf2f(h));
        }
        *reinterpret_cast<ushort4*>(&out_hi[obase + g*4]) = sh;
        *reinterpret_cast<ushort4*>(&out_lo[obase + g*4]) = sl;
    }
}

// ===================== split-bf16 MFMA stride-2 conv v2 ====================
// Wave tile: 64co x 64px (NT=4, S=4). NW co-waves per block.
// NPACK=1: one sample, 8x8 out tile. NPACK=4: four samples, 4x4 out each.
template<int CI,int CO,int HO,int NW,int NPACK>
__global__ __launch_bounds__(NW*64, 2)
void bb_conv_v2(const unsigned short* __restrict__ in_hi,
                const unsigned short* __restrict__ in_lo,
                const unsigned short* __restrict__ Whi,
                const unsigned short* __restrict__ Wlo,
                const float* __restrict__ Bias,
                unsigned short* __restrict__ out_hi,
                unsigned short* __restrict__ out_lo)
{
    constexpr int HI = HO*2;
    constexpr int TH = (NPACK==1) ? 8 : 4;
    constexpr int TW = TH;
    constexpr int R  = 2*TH+1, C = 2*TW+1;
    constexpr int CK = 32;
    constexpr int PITCH = CK + 8;              // 40 ushorts
    constexpr int CO_T  = NW*64;
    constexpr int NTHR  = NW*64;

    __shared__ __align__(16) unsigned short hi_lds[NPACK*R*C*PITCH];
    __shared__ __align__(16) unsigned short lo_lds[NPACK*R*C*PITCH];

    const int n0  = blockIdx.z * NPACK;
    const int co0 = blockIdx.y * CO_T;
    constexpr int TILES_X = (NPACK==1) ? (HO/TW) : 1;
    const int ty = blockIdx.x / TILES_X, tx = blockIdx.x % TILES_X;
    const int oh0 = ty*TH, ow0 = tx*TW;
    const int r0 = 2*oh0, c0 = 2*ow0;

    const int t = threadIdx.x;
    const int w = t >> 6, lane = t & 63;
    const int s = lane & 15, q = lane >> 4;

    // px mapping (B-frag / D-col): NPACK=1: si = px subtile; NPACK=4: si = sample
    int dyy[4], dxx[4], tb[4];
    #pragma unroll
    for (int si = 0; si < 4; ++si) {
        if (NPACK == 1) { dyy[si] = si*2 + (s>>3); dxx[si] = s & 7; tb[si] = 0; }
        else            { dyy[si] = s >> 2;        dxx[si] = s & 3; tb[si] = si*R*C*PITCH; }
    }

    int wrow[4];
    #pragma unroll
    for (int tn = 0; tn < 4; ++tn)
        wrow[tn] = (co0 + w*64 + tn*16 + s)*9*CI + q*8;

    f32x4 acc[4][4];
    #pragma unroll
    for (int si = 0; si < 4; ++si)
        #pragma unroll
        for (int tn = 0; tn < 4; ++tn)
            acc[si][tn] = (f32x4){0.f,0.f,0.f,0.f};

    for (int ci0 = 0; ci0 < CI; ci0 += CK) {
        // ---- stage hi & lo input tiles ----
        constexpr int C8  = CK/8;
        constexpr int PXW = R*C*C8;
        for (int i8 = t; i8 < NPACK*PXW; i8 += NTHR) {
            int ti = i8 / PXW, rem = i8 % PXW;
            int pix = rem / C8, cs = rem % C8;
            int r = pix / C, c = pix % C;
            int ih = r0 + r, iw = c0 + c;
            uint4 vh = {0u,0u,0u,0u}, vl = {0u,0u,0u,0u};
            if (ih < HI && iw < HI) {
                long off = (((long)(n0+ti)*HI + ih)*HI + iw)*CI + ci0 + cs*8;
                vh = *reinterpret_cast<const uint4*>(&in_hi[off]);
                vl = *reinterpret_cast<const uint4*>(&in_lo[off]);
            }
            *reinterpret_cast<uint4*>(&hi_lds[(ti*R*C + pix)*PITCH + cs*8]) = vh;
            *reinterpret_cast<uint4*>(&lo_lds[(ti*R*C + pix)*PITCH + cs*8]) = vl;
        }
        __syncthreads();

        // ---- 2-buffer tap pipeline over the 9 taps ----
        bf16x8 ah[2][4], al[2][4];
        #pragma unroll
        for (int tn = 0; tn < 4; ++tn) {
            const int wo = wrow[tn] + ci0;
            ah[0][tn] = *reinterpret_cast<const bf16x8*>(&Whi[wo]);
            al[0][tn] = *reinterpret_cast<const bf16x8*>(&Wlo[wo]);
        }
        #pragma unroll
        for (int k = 0; k < 9; ++k) {
            const int cur = k & 1, nxt = cur ^ 1;
            if (k < 8) {
                #pragma unroll
                for (int tn = 0; tn < 4; ++tn) {
                    const int wo = wrow[tn] + (k+1)*CI + ci0;
                    ah[nxt][tn] = *reinterpret_cast<const bf16x8*>(&Whi[wo]);
                    al[nxt][tn] = *reinterpret_cast<const bf16x8*>(&Wlo[wo]);
                }
            }
            const int kh = k/3, kw = k%3;
            bf16x8 bh[4], bl[4];
            #pragma unroll
            for (int si = 0; si < 4; ++si) {
                const int pi = tb[si] + ((2*dyy[si]+kh)*C + 2*dxx[si]+kw)*PITCH + q*8;
                bh[si] = *reinterpret_cast<const bf16x8*>(&hi_lds[pi]);
                bl[si] = *reinterpret_cast<const bf16x8*>(&lo_lds[pi]);
            }
            #pragma unroll
            for (int si = 0; si < 4; ++si)
                #pragma unroll
                for (int tn = 0; tn < 4; ++tn) {
                    acc[si][tn] = __builtin_amdgcn_mfma_f32_16x16x32_bf16(ah[cur][tn], bh[si], acc[si][tn], 0,0,0);
                    acc[si][tn] = __builtin_amdgcn_mfma_f32_16x16x32_bf16(ah[cur][tn], bl[si], acc[si][tn], 0,0,0);
                    acc[si][tn] = __builtin_amdgcn_mfma_f32_16x16x32_bf16(al[cur][tn], bh[si], acc[si][tn], 0,0,0);
                }
        }
        __syncthreads();
    }

    // ---- epilogue: bias + relu + split store ----
    #pragma unroll
    for (int si = 0; si < 4; ++si) {
        const int n_s = (NPACK==1) ? n0 : (n0 + si);
        const int oh  = (NPACK==1) ? (oh0 + dyy[si]) : dyy[si];
        const int ow  = (NPACK==1) ? (ow0 + dxx[si]) : dxx[si];
        #pragma unroll
        for (int tn = 0; tn < 4; ++tn) {
            int co_b = co0 + w*64 + tn*16 + q*4;
            ushort4 sh, sl;
            #pragma unroll
            for (int r = 0; r < 4; ++r) {
                float v = fmaxf(acc[si][tn][r] + Bias[co_b + r], 0.f);
                unsigned short h = f2bf(v);
                ((unsigned short*)&sh)[r] = h;
                ((unsigned short*)&sl)[r] = f2bf(v - bf2f(h));
            }
            long ob = (((long)n_s*HO + oh)*HO + ow)*CO + co_b;
            *reinterpret_cast<ushort4*>(&out_hi[ob]) = sh;
            *reinterpret_cast<ushort4*>(&out_lo[ob]) = sl;
        }
    }
}

// ===================== weight transforms ===================================
template<int CI>
__global__ __launch_bounds__(256)
void wtrans_split_kernel(const float* __restrict__ src,
                         unsigned short* __restrict__ hi,
                         unsigned short* __restrict__ lo)
{
    __shared__ float buf[CI*9];
    const long blk = blockIdx.x;
    const float* sp = src + blk*(CI*9);
    for (int i = threadIdx.x; i < CI*9; i += 256) buf[i] = sp[i];
    __syncthreads();
    for (int i = threadIdx.x; i < CI*9; i += 256) {
        int k = i / CI, ci = i % CI;
        float v = buf[ci*9 + k];
        unsigned short h = f2bf(v);
        hi[blk*(CI*9) + i] = h;
        lo[blk*(CI*9) + i] = f2bf(v - bf2f(h));
    }
}

template<int CI>
__global__ __launch_bounds__(256)
void wtrans_kernel(const float* __restrict__ src, unsigned short* __restrict__ dst)
{
    __shared__ float buf[CI*9];
    const long blk = blockIdx.x;
    const float* sp = src + blk*(CI*9);
    for (int i = threadIdx.x; i < CI*9; i += 256) buf[i] = sp[i];
    __syncthreads();
    unsigned short* d = dst + blk*(CI*9);
    for (int i = threadIdx.x; i < CI*9; i += 256) {
        int k = i / CI, ci = i % CI;
        d[i] = f2bf(buf[ci*9 + k]);
    }
}

// ===================== classifier path =====================================
__global__ __launch_bounds__(256) void pool_kernel(const unsigned short* __restrict__ fh,
                                                   const unsigned short* __restrict__ fl,
                                                   float* __restrict__ pooled)
{
    int i = blockIdx.x*256 + threadIdx.x;
    if (i < 64*512) {
        int n = i >> 9, ci = i & 511;
        const unsigned short* ph = fh + (long)n*8192 + ci;
        const unsigned short* pl = fl + (long)n*8192 + ci;
        float sacc = 0.f;
        #pragma unroll
        for (int px = 0; px < 16; ++px)
            sacc += bf2f(ph[px*512]) + bf2f(pl[px*512]);
        pooled[i] = sacc * (1.f/16.f);
    }
}

__global__ __launch_bounds__(256) void fc1_kernel(const float* __restrict__ pooled,
                                                  const float* __restrict__ Wc1,
                                                  const float* __restrict__ bc1,
                                                  float* __restrict__ hidden)
{
    int i = blockIdx.x*256 + threadIdx.x;
    if (i < 64*128) {
        int n = i/128, j = i%128;
        const float* p = pooled + n*512;
        const float* w = Wc1 + j*512;
        float sacc = 0.f;
        for (int k = 0; k < 512; ++k) sacc += p[k]*w[k];
        hidden[i] = fmaxf(sacc + bc1[j], 0.f);
    }
}

__global__ __launch_bounds__(64) void fc2_kernel(const float* __restrict__ hidden,
                                                 const float* __restrict__ Wc2,
                                                 const float* __restrict__ bc2,
                                                 float* __restrict__ out,
                                                 int* __restrict__ cls_i)
{
    int n = blockIdx.x;
    int j = threadIdx.x;
    __shared__ float lg[5];
    if (j < 5) {
        const float* h = hidden + n*128;
        const float* w = Wc2 + j*128;
        float sacc = 0.f;
        for (int k = 0; k < 128; ++k) sacc += h[k]*w[k];
        sacc += bc2[j];
        out[n*5 + j] = sacc;
        lg[j] = sacc;
    }
    __syncthreads();
    if (j == 0) {
        int am = 0; float best = lg[0];
        #pragma unroll
        for (int k = 1; k < 5; ++k) if (lg[k] > best) { best = lg[k]; am = k; }
        out[320 + n] = (float)am;
        cls_i[n] = am;
    }
}

// ===================== bf16 MFMA decoder conv v2 (dec1-3) ==================
// Fused up2+conv3x3. Wave tile: 64co x 64px (NT=4, S=4), NW co-waves/block.
// 8x8 out tile per block; CK=64.
template<int CI,int CO,int HO,int NW>
__global__ __launch_bounds__(NW*64, 2)
void dec_conv_v2(const unsigned short* __restrict__ in,
                 const unsigned short* __restrict__ WT,
                 const float* __restrict__ Be,
                 const int* __restrict__ cls_i,
                 unsigned short* __restrict__ out)
{
    constexpr int HI = HO/2;
    constexpr int R = 6, C = 6;                 // 8/2 + 2
    constexpr int CK = 64, CKQ = CK/32;
    constexpr int PITCH = CK + 8;               // 72 ushorts
    constexpr int CO_T = NW*64;
    constexpr int NTHR = NW*64;

    __shared__ __align__(16) unsigned short ilds[R*C*PITCH];

    const int n = blockIdx.z;
    const int e = cls_i[n];
    const int co0 = blockIdx.y * CO_T;
    constexpr int TILES_X = HO/8;
    const int ty = blockIdx.x / TILES_X, tx = blockIdx.x % TILES_X;
    const int oh0 = ty*8, ow0 = tx*8;
    const int ih0 = oh0/2 - 1, iw0 = ow0/2 - 1;

    const int t = threadIdx.x;
    const int w = t >> 6, lane = t & 63;
    const int s = lane & 15, q = lane >> 4;

    const unsigned short* Wbase = WT + (long)e*CO*9*CI;
    const unsigned short* inN   = in + (long)n*HI*HI*CI;

    int dyy[4], dxx[4];
    #pragma unroll
    for (int si = 0; si < 4; ++si) { dyy[si] = si*2 + (s>>3); dxx[si] = s & 7; }

    long wrow[4];
    #pragma unroll
    for (int tn = 0; tn < 4; ++tn)
        wrow[tn] = (long)(co0 + w*64 + tn*16 + s)*9*CI + q*8;

    f32x4 acc[4][4];
    #pragma unroll
    for (int si = 0; si < 4; ++si)
        #pragma unroll
        for (int tn = 0; tn < 4; ++tn)
            acc[si][tn] = (f32x4){0.f,0.f,0.f,0.f};

    for (int ci0 = 0; ci0 < CI; ci0 += CK) {
        constexpr int C8 = CK/8;
        for (int i8 = t; i8 < R*C*C8; i8 += NTHR) {
            int pix = i8 / C8, cs = i8 % C8;
            int r = pix / C, c = pix % C;
            int ih = ih0 + r, iw = iw0 + c;
            uint4 v = {0u,0u,0u,0u};
            if (ih >= 0 && ih < HI && iw >= 0 && iw < HI)
                v = *reinterpret_cast<const uint4*>(&inN[((long)ih*HI + iw)*CI + ci0 + cs*8]);
            *reinterpret_cast<uint4*>(&ilds[pix*PITCH + cs*8]) = v;
        }
        __syncthreads();

        // ---- 2-buffer pipeline over 18 (tap, ci-half) steps ----
        bf16x8 a[2][4];
        #pragma unroll
        for (int tn = 0; tn < 4; ++tn)
            a[0][tn] = *reinterpret_cast<const bf16x8*>(&Wbase[wrow[tn] + ci0]);
        #pragma unroll
        for (int st = 0; st < 9*CKQ; ++st) {
            const int cur = st & 1, nxt = cur ^ 1;
            if (st + 1 < 9*CKQ) {
                const int kp = (st+1)/CKQ, cp = (st+1)%CKQ;
                #pragma unroll
                for (int tn = 0; tn < 4; ++tn)
                    a[nxt][tn] = *reinterpret_cast<const bf16x8*>(
                        &Wbase[wrow[tn] + kp*CI + ci0 + cp*32]);
            }
            const int k = st/CKQ, ckq = st%CKQ;
            const int kh = k/3, kw = k%3;
            #pragma unroll
            for (int si = 0; si < 4; ++si) {
                const int ihr = ((dyy[si] + kh - 1) >> 1) + 1;
                const int iwr = ((dxx[si] + kw - 1) >> 1) + 1;
                bf16x8 b = *reinterpret_cast<const bf16x8*>(
                    &ilds[(ihr*C + iwr)*PITCH + ckq*32 + q*8]);
                #pragma unroll
                for (int tn = 0; tn < 4; ++tn)
                    acc[si][tn] = __builtin_amdgcn_mfma_f32_16x16x32_bf16(
                        a[cur][tn], b, acc[si][tn], 0, 0, 0);
            }
        }
        __syncthreads();
    }

    #pragma unroll
    for (int si = 0; si < 4; ++si) {
        int oh = oh0 + dyy[si], ow = ow0 + dxx[si];
        #pragma unroll
        for (int tn = 0; tn < 4; ++tn) {
            int co_b = co0 + w*64 + tn*16 + q*4;
            ushort4 st4;
            #pragma unroll
            for (int r = 0; r < 4; ++r) {
                float v = acc[si][tn][r] + Be[e*CO + co_b + r];
                v = fmaxf(v, 0.f);
                ((unsigned short*)&st4)[r] = f2bf(v);
            }
            *reinterpret_cast<ushort4*>(&out[(((long)n*HO + oh)*HO + ow)*CO + co_b]) = st4;
        }
    }
}

// ===================== bf16 MFMA decoder conv (dec4/5, unchanged) ==========
template<int CI,int CO,int HO,int TH,int TW,int CO_T,int CK>
__global__ __launch_bounds__(256, 2)
void dec_conv_kernel(const unsigned short* __restrict__ in,
                     const unsigned short* __restrict__ WT,
                     const float* __restrict__ Be,
                     const int* __restrict__ cls_i,
                     unsigned short* __restrict__ out)
{
    constexpr int HI = HO/2;
    constexpr int R = TH/2 + 2, C = TW/2 + 2;
    constexpr int PITCH = CK + 8;
    constexpr int NT = CO_T/16;
    constexpr int S  = (TH*TW)/64;
    constexpr int SXT = TW/8;
    constexpr int CKQ = CK/32;
    constexpr int NST = 9*CKQ;
    constexpr int PF  = 3;

    __shared__ __align__(16) unsigned short ilds[R*C*PITCH];

    const int n = blockIdx.z;
    const int e = cls_i[n];
    const int co0 = blockIdx.y * CO_T;
    constexpr int TILES_X = HO/TW;
    const int ty = blockIdx.x / TILES_X, tx = blockIdx.x % TILES_X;
    const int oh0 = ty*TH, ow0 = tx*TW;
    const int ih0 = oh0/2 - 1, iw0 = ow0/2 - 1;

    const int t = threadIdx.x;
    const int w = t >> 6;
    const int lane = t & 63;
    const int s = lane & 15;
    const int q = lane >> 4;

    const unsigned short* Wbase = WT + ((long)e*CO + co0)*9*CI;
    const unsigned short* inN   = in + (long)n*HI*HI*CI;

    int wrow[NT];
    #pragma unroll
    for (int tn = 0; tn < NT; ++tn)
        wrow[tn] = (tn*16 + s)*9*CI + q*8;

    f32x4 acc[S][NT];
    #pragma unroll
    for (int si = 0; si < S; ++si)
        #pragma unroll
        for (int tn = 0; tn < NT; ++tn)
            acc[si][tn] = (f32x4){0.f,0.f,0.f,0.f};

    int dy[S], dx[S];
    #pragma unroll
    for (int si = 0; si < S; ++si) {
        int sub = w + si*4;
        int sy = sub / SXT, sx = sub % SXT;
        dy[si] = sy*2 + (s >> 3);
        dx[si] = sx*8 + (s & 7);
    }

    for (int ci0 = 0; ci0 < CI; ci0 += CK) {
        constexpr int C8 = CK/8;
        for (int i8 = t; i8 < R*C*C8; i8 += 256) {
            int pix = i8 / C8, cs = i8 % C8;
            int r = pix / C, c = pix % C;
            int ih = ih0 + r, iw = iw0 + c;
            uint4 v = {0u,0u,0u,0u};
            if (ih >= 0 && ih < HI && iw >= 0 && iw < HI)
                v = *reinterpret_cast<const uint4*>(&inN[((long)ih*HI + iw)*CI + ci0 + cs*8]);
            *reinterpret_cast<uint4*>(&ilds[pix*PITCH + cs*8]) = v;
        }
        __syncthreads();

        bf16x8 a[NST][NT];
        #pragma unroll
        for (int pf = 0; pf < PF && pf < NST; ++pf)
            #pragma unroll
            for (int tn = 0; tn < NT; ++tn) {
                const int k = pf/CKQ, ckq = pf%CKQ;
                a[pf][tn] = *reinterpret_cast<const bf16x8*>(
                    &Wbase[wrow[tn] + k*CI + ci0 + ckq*32]);
            }
        #pragma unroll
        for (int st = 0; st < NST; ++st) {
            if (st + PF < NST) {
                const int kp = (st+PF)/CKQ, cp = (st+PF)%CKQ;
                #pragma unroll
                for (int tn = 0; tn < NT; ++tn)
                    a[st+PF][tn] = *reinterpret_cast<const bf16x8*>(
                        &Wbase[wrow[tn] + kp*CI + ci0 + cp*32]);
            }
            const int k = st/CKQ, ckq = st%CKQ;
            const int kh = k/3, kw = k%3;
            #pragma unroll
            for (int si = 0; si < S; ++si) {
                int ihr = ((dy[si] + kh - 1) >> 1) + 1;
                int iwr = ((dx[si] + kw - 1) >> 1) + 1;
                bf16x8 b = *reinterpret_cast<const bf16x8*>(
                    &ilds[(ihr*C + iwr)*PITCH + ckq*32 + q*8]);
                #pragma unroll
                for (int tn = 0; tn < NT; ++tn)
                    acc[si][tn] = __builtin_amdgcn_mfma_f32_16x16x32_bf16(
                        a[st][tn], b, acc[si][tn], 0, 0, 0);
            }
        }
        __syncthreads();
    }

    #pragma unroll
    for (int si = 0; si < S; ++si) {
        int oh = oh0 + dy[si], ow = ow0 + dx[si];
        #pragma unroll
        for (int tn = 0; tn < NT; ++tn) {
            int co_b = co0 + tn*16 + q*4;
            ushort4 st4;
            #pragma unroll
            for (int r = 0; r < 4; ++r) {
                float v = acc[si][tn][r] + Be[e*CO + co_b + r];
                v = fmaxf(v, 0.f);
                ((unsigned short*)&st4)[r] = f2bf(v);
            }
            *reinterpret_cast<ushort4*>(&out[(((long)n*HO + oh)*HO + ow)*CO + co_b]) = st4;
        }
    }
}

// ===================== 1x1 head: NHWC bf16 -> NCHW fp32 ====================
__global__ __launch_bounds__(256) void head_kernel(const unsigned short* __restrict__ d5,
                                                   const float* __restrict__ Wh,
                                                   const float* __restrict__ bh,
                                                   const int* __restrict__ cls_i,
                                                   float* __restrict__ seg)
{
    int n = blockIdx.y;
    int p = blockIdx.x*256 + threadIdx.x;
    __shared__ float w[85];
    int e = cls_i[n];
    if (threadIdx.x < 80) w[threadIdx.x] = Wh[(long)e*80 + threadIdx.x];
    if (threadIdx.x < 5)  w[80+threadIdx.x] = bh[e*5 + threadIdx.x];
    __syncthreads();
    const unsigned short* dp = d5 + ((long)n*16384 + p)*16;
    uint4 u0 = *reinterpret_cast<const uint4*>(dp);
    uint4 u1 = *reinterpret_cast<const uint4*>(dp + 8);
    float x[16];
    unsigned int uu[4] = {u0.x, u0.y, u0.z, u0.w};
    unsigned int vv[4] = {u1.x, u1.y, u1.z, u1.w};
    #pragma unroll
    for (int i = 0; i < 4; ++i) {
        x[2*i+0] = __uint_as_float(uu[i] << 16);
        x[2*i+1] = __uint_as_float(uu[i] & 0xffff0000u);
        x[8+2*i+0] = __uint_as_float(vv[i] << 16);
        x[8+2*i+1] = __uint_as_float(vv[i] & 0xffff0000u);
    }
    #pragma unroll
    for (int co = 0; co < 5; ++co) {
        float sacc = w[80+co];
        #pragma unroll
        for (int ci = 0; ci < 16; ++ci) sacc += x[ci]*w[co*16+ci];
        seg[((long)n*5 + co)*16384 + p] = sacc;
    }
}

// ===========================================================================
extern "C" void kernel_launch(void* const* d_in, const int* in_sizes, int n_in,
                              void* d_out, int out_size, void* d_ws, size_t ws_size,
                              hipStream_t stream)
{
    const float* x   = (const float*)d_in[0];
    const float* Wb1 = (const float*)d_in[1];  const float* bb1 = (const float*)d_in[2];
    const float* Wb2 = (const float*)d_in[3];  const float* bb2 = (const float*)d_in[4];
    const float* Wb3 = (const float*)d_in[5];  const float* bb3 = (const float*)d_in[6];
    const float* Wb4 = (const float*)d_in[7];  const float* bb4 = (const float*)d_in[8];
    const float* Wb5 = (const float*)d_in[9];  const float* bb5 = (const float*)d_in[10];
    const float* Wc1 = (const float*)d_in[11]; const float* bc1 = (const float*)d_in[12];
    const float* Wc2 = (const float*)d_in[13]; const float* bc2 = (const float*)d_in[14];
    const float* We1 = (const float*)d_in[15]; const float* be1 = (const float*)d_in[16];
    const float* We2 = (const float*)d_in[17]; const float* be2 = (const float*)d_in[18];
    const float* We3 = (const float*)d_in[19]; const float* be3 = (const float*)d_in[20];
    const float* We4 = (const float*)d_in[21]; const float* be4 = (const float*)d_in[22];
    const float* We5 = (const float*)d_in[23]; const float* be5 = (const float*)d_in[24];
    const float* We6 = (const float*)d_in[25]; const float* be6 = (const float*)d_in[26];

    float* out = (float*)d_out;
    char* ws = (char*)d_ws;

    // ---- X region (67 MB): H1 -> {H3, WB4/5} -> {P, Q, WT1-5} ----
    unsigned short* H1hi = (unsigned short*)(ws + 0);
    unsigned short* H1lo = (unsigned short*)(ws + 33554432);
    unsigned short* H3hi = (unsigned short*)(ws + 0);
    unsigned short* H3lo = (unsigned short*)(ws + 8388608);
    unsigned short* WB4hi = (unsigned short*)(ws + 16777216);
    unsigned short* WB4lo = (unsigned short*)(ws + 19136512);
    unsigned short* WB5hi = (unsigned short*)(ws + 21495808);
    unsigned short* WB5lo = (unsigned short*)(ws + 26214400);
    unsigned short* P    = (unsigned short*)(ws + 0);
    unsigned short* Q    = (unsigned short*)(ws + 33554432);
    unsigned short* WT1  = (unsigned short*)(ws + 50331648);
    unsigned short* WT2  = (unsigned short*)(ws + 62128128);
    unsigned short* WT3  = (unsigned short*)(ws + 65077248);
    unsigned short* WT4  = (unsigned short*)(ws + 65814528);
    unsigned short* WT5  = (unsigned short*)(ws + 65998848);

    // ---- Y region (33.5 MB): H2 -> {H4, FEATS, pooled/hidden/cls} ----
    char* Y = ws + 67108864;
    unsigned short* H2hi = (unsigned short*)(Y + 0);
    unsigned short* H2lo = (unsigned short*)(Y + 16777216);
    unsigned short* H4hi = (unsigned short*)(Y + 0);
    unsigned short* H4lo = (unsigned short*)(Y + 4194304);
    unsigned short* FShi = (unsigned short*)(Y + 8388608);
    unsigned short* FSlo = (unsigned short*)(Y + 9437184);
    float* pooled = (float*)(Y + 10485760);
    float* hidden = (float*)(Y + 10616832);
    int*   cls_i  = (int*)(Y + 10649600);

    // ---- W23 tail (1.5 MB) ----
    char* W23 = ws + 100663296;
    unsigned short* WB2hi = (unsigned short*)(W23 + 0);
    unsigned short* WB2lo = (unsigned short*)(W23 + 147456);
    unsigned short* WB3hi = (unsigned short*)(W23 + 294912);
    unsigned short* WB3lo = (unsigned short*)(W23 + 884736);

    // ---- backbone weight transposes (conv2/3 only; 4/5 after conv2) ----
    hipLaunchKernelGGL((wtrans_split_kernel<64>),  dim3(128), dim3(256), 0, stream, Wb2, WB2hi, WB2lo);
    hipLaunchKernelGGL((wtrans_split_kernel<128>), dim3(256), dim3(256), 0, stream, Wb3, WB3hi, WB3lo);

    // ---- conv1 (fp32 direct, split output) ----
    hipLaunchKernelGGL(conv1_kernel, dim3(64,2,64), dim3(256), 0, stream, x, Wb1, bb1, H1hi, H1lo);

    // ---- conv2: 64px x 128co blocks (2 waves) ----
    hipLaunchKernelGGL((bb_conv_v2<64,128,32,2,1>), dim3(16,1,64), dim3(128), 0, stream,
                       H1hi, H1lo, WB2hi, WB2lo, bb2, H2hi, H2lo);

    // ---- H1 dead: transpose conv4/5 + decoder weights into X ----
    hipLaunchKernelGGL((wtrans_split_kernel<256>), dim3(512), dim3(256), 0, stream, Wb4, WB4hi, WB4lo);
    hipLaunchKernelGGL((wtrans_split_kernel<512>), dim3(512), dim3(256), 0, stream, Wb5, WB5hi, WB5lo);
    hipLaunchKernelGGL((wtrans_kernel<512>), dim3(5*256), dim3(256), 0, stream, We1, WT1);
    hipLaunchKernelGGL((wtrans_kernel<256>), dim3(5*128), dim3(256), 0, stream, We2, WT2);
    hipLaunchKernelGGL((wtrans_kernel<128>), dim3(5*64),  dim3(256), 0, stream, We3, WT3);
    hipLaunchKernelGGL((wtrans_kernel<64>),  dim3(5*32),  dim3(256), 0, stream, We4, WT4);
    hipLaunchKernelGGL((wtrans_kernel<32>),  dim3(5*16),  dim3(256), 0, stream, We5, WT5);

    // ---- conv3..5 ----
    hipLaunchKernelGGL((bb_conv_v2<128,256,16,2,1>), dim3(4,2,64), dim3(128), 0, stream,
                       H2hi, H2lo, WB3hi, WB3lo, bb3, H3hi, H3lo);
    hipLaunchKernelGGL((bb_conv_v2<256,512, 8,2,1>), dim3(1,4,64), dim3(128), 0, stream,
                       H3hi, H3lo, WB4hi, WB4lo, bb4, H4hi, H4lo);
    hipLaunchKernelGGL((bb_conv_v2<512,512, 4,2,4>), dim3(1,4,16), dim3(128), 0, stream,
                       H4hi, H4lo, WB5hi, WB5lo, bb5, FShi, FSlo);

    // ---- classifier ----
    hipLaunchKernelGGL(pool_kernel, dim3(128), dim3(256), 0, stream, FShi, FSlo, pooled);
    hipLaunchKernelGGL(fc1_kernel,  dim3(32),  dim3(256), 0, stream, pooled, Wc1, bc1, hidden);
    hipLaunchKernelGGL(fc2_kernel,  dim3(64),  dim3(64),  0, stream, hidden, Wc2, bc2, out, cls_i);

    // ---- decoder: FShi -> P -> Q -> P -> Q -> P ----
    hipLaunchKernelGGL((dec_conv_v2<512,256,  8,4>), dim3(1, 1,64), dim3(256), 0, stream, FShi, WT1, be1, cls_i, P);
    hipLaunchKernelGGL((dec_conv_v2<256,128, 16,2>), dim3(4, 1,64), dim3(128), 0, stream, P,    WT2, be2, cls_i, Q);
    hipLaunchKernelGGL((dec_conv_v2<128, 64, 32,1>), dim3(16,1,64), dim3(64),  0, stream, Q,    WT3, be3, cls_i, P);
    hipLaunchKernelGGL((dec_conv_kernel< 64, 32, 64, 16,16, 32,64>), dim3(16, 1,64), dim3(256), 0, stream, P, We4 ? WT4 : WT4, be4, cls_i, Q);
    hipLaunchKernelGGL((dec_conv_kernel< 32, 16,128, 16,16, 16,32>), dim3(64, 1,64), dim3(256), 0, stream, Q, WT5, be5, cls_i, P);

    // ---- 1x1 head -> seg (NCHW fp32) ----
    hipLaunchKernelGGL(head_kernel, dim3(64,64), dim3(256), 0, stream, P, We6, be6, cls_i, out + 384);
}

// Round 6
// 689.727 us; speedup vs baseline: 4.0504x; 1.2750x over previous
//
#include <hip/hip_runtime.h>
#include <hip/hip_bf16.h>

// ---------------------------------------------------------------------------
// R6: R5 + split-K restructure of the two grid-starved GEMMs:
//   conv5 (was 194us @ 1.4% occupancy, 64 blocks) -> 8-way ci-split partials
//   dec1  (64 blocks)                             -> 4-way ci-split partials
// Partials in f32 to dead workspace regions; tiny reduce kernels fuse
// bias+relu(+hi/lo split / expert bias).
// ---------------------------------------------------------------------------

typedef __attribute__((ext_vector_type(8))) short bf16x8;   // 8 bf16 = 4 VGPRs
typedef __attribute__((ext_vector_type(4))) float f32x4;

static __device__ __forceinline__ unsigned short f2bf(float f) {
    __hip_bfloat16 h = __float2bfloat16(f);
    return *reinterpret_cast<unsigned short*>(&h);
}
static __device__ __forceinline__ float bf2f(unsigned short u) {
    return __uint_as_float(((unsigned int)u) << 16);
}

// ===================== conv1: fp32 direct, split NHWC output ===============
__global__ __launch_bounds__(256)
void conv1_kernel(const float* __restrict__ in, const float* __restrict__ W,
                  const float* __restrict__ Bias,
                  unsigned short* __restrict__ out_hi,
                  unsigned short* __restrict__ out_lo)
{
    constexpr int R = 17, C = 17;
    __shared__ float ilds[3*R*C];
    __shared__ float wlds[27*32];
    const int n = blockIdx.z, co0 = blockIdx.y*32;
    const int ty = blockIdx.x >> 3, tx = blockIdx.x & 7;
    const int oh0 = ty*8, ow0 = tx*8;
    const int t = threadIdx.x, p = t & 63, grp = t >> 6;
    const int py = p >> 3, px = p & 7;
    const int r0 = 2*oh0, c0 = 2*ow0;

    const float* ibase = in + (long)n*3*16384;
    for (int idx = t; idx < 3*R*C; idx += 256) {
        int ck = idx/(R*C), rc = idx%(R*C);
        int r = rc/C, c = rc%C;
        int ih = r0+r, iw = c0+c;
        float v = 0.f;
        if (ih < 128 && iw < 128) v = ibase[ck*16384 + ih*128 + iw];
        ilds[idx] = v;
    }
    for (int idx = t; idx < 32*27; idx += 256) {
        int co = idx & 31, rem = idx >> 5;
        wlds[rem*32 + co] = W[(co0+co)*27 + rem];
    }
    __syncthreads();

    float acc[8];
    #pragma unroll
    for (int i=0;i<8;i++) acc[i]=0.f;

    #pragma unroll
    for (int ck = 0; ck < 3; ++ck) {
        float xv[9];
        #pragma unroll
        for (int kh = 0; kh < 3; ++kh)
            #pragma unroll
            for (int kw = 0; kw < 3; ++kw)
                xv[kh*3+kw] = ilds[ck*289 + (2*py+kh)*17 + 2*px+kw];
        #pragma unroll
        for (int k = 0; k < 9; ++k) {
            #pragma unroll
            for (int g = 0; g < 2; ++g) {
                const float4 w = *reinterpret_cast<const float4*>(
                    &wlds[(ck*9+k)*32 + grp*8 + g*4]);
                acc[g*4+0] += xv[k]*w.x;
                acc[g*4+1] += xv[k]*w.y;
                acc[g*4+2] += xv[k]*w.z;
                acc[g*4+3] += xv[k]*w.w;
            }
        }
    }

    const long obase = (((long)n*64 + oh0+py)*64 + ow0+px)*64 + co0 + grp*8;
    #pragma unroll
    for (int g = 0; g < 2; ++g) {
        ushort4 sh, sl;
        #pragma unroll
        for (int j = 0; j < 4; ++j) {
            int co = co0 + grp*8 + g*4 + j;
            float v = fmaxf(acc[g*4+j] + Bias[co], 0.f);
            unsigned short h = f2bf(v);
            ((unsigned short*)&sh)[j] = h;
            ((unsigned short*)&sl)[j] = f2bf(v - bf2f(h));
        }
        *reinterpret_cast<ushort4*>(&out_hi[obase + g*4]) = sh;
        *reinterpret_cast<ushort4*>(&out_lo[obase + g*4]) = sl;
    }
}

// ===================== split-bf16 MFMA stride-2 conv v2 (conv2-4) ==========
// Wave tile: 64co x 64px (NT=4, S=4). NW co-waves per block. NPACK=1 only.
template<int CI,int CO,int HO,int NW,int NPACK>
__global__ __launch_bounds__(NW*64, 2)
void bb_conv_v2(const unsigned short* __restrict__ in_hi,
                const unsigned short* __restrict__ in_lo,
                const unsigned short* __restrict__ Whi,
                const unsigned short* __restrict__ Wlo,
                const float* __restrict__ Bias,
                unsigned short* __restrict__ out_hi,
                unsigned short* __restrict__ out_lo)
{
    constexpr int HI = HO*2;
    constexpr int TH = (NPACK==1) ? 8 : 4;
    constexpr int TW = TH;
    constexpr int R  = 2*TH+1, C = 2*TW+1;
    constexpr int CK = 32;
    constexpr int PITCH = CK + 8;
    constexpr int CO_T  = NW*64;
    constexpr int NTHR  = NW*64;

    __shared__ __align__(16) unsigned short hi_lds[NPACK*R*C*PITCH];
    __shared__ __align__(16) unsigned short lo_lds[NPACK*R*C*PITCH];

    const int n0  = blockIdx.z * NPACK;
    const int co0 = blockIdx.y * CO_T;
    constexpr int TILES_X = (NPACK==1) ? (HO/TW) : 1;
    const int ty = blockIdx.x / TILES_X, tx = blockIdx.x % TILES_X;
    const int oh0 = ty*TH, ow0 = tx*TW;
    const int r0 = 2*oh0, c0 = 2*ow0;

    const int t = threadIdx.x;
    const int w = t >> 6, lane = t & 63;
    const int s = lane & 15, q = lane >> 4;

    int dyy[4], dxx[4], tb[4];
    #pragma unroll
    for (int si = 0; si < 4; ++si) {
        if (NPACK == 1) { dyy[si] = si*2 + (s>>3); dxx[si] = s & 7; tb[si] = 0; }
        else            { dyy[si] = s >> 2;        dxx[si] = s & 3; tb[si] = si*R*C*PITCH; }
    }

    int wrow[4];
    #pragma unroll
    for (int tn = 0; tn < 4; ++tn)
        wrow[tn] = (co0 + w*64 + tn*16 + s)*9*CI + q*8;

    f32x4 acc[4][4];
    #pragma unroll
    for (int si = 0; si < 4; ++si)
        #pragma unroll
        for (int tn = 0; tn < 4; ++tn)
            acc[si][tn] = (f32x4){0.f,0.f,0.f,0.f};

    for (int ci0 = 0; ci0 < CI; ci0 += CK) {
        constexpr int C8  = CK/8;
        constexpr int PXW = R*C*C8;
        for (int i8 = t; i8 < NPACK*PXW; i8 += NTHR) {
            int ti = i8 / PXW, rem = i8 % PXW;
            int pix = rem / C8, cs = rem % C8;
            int r = pix / C, c = pix % C;
            int ih = r0 + r, iw = c0 + c;
            uint4 vh = {0u,0u,0u,0u}, vl = {0u,0u,0u,0u};
            if (ih < HI && iw < HI) {
                long off = (((long)(n0+ti)*HI + ih)*HI + iw)*CI + ci0 + cs*8;
                vh = *reinterpret_cast<const uint4*>(&in_hi[off]);
                vl = *reinterpret_cast<const uint4*>(&in_lo[off]);
            }
            *reinterpret_cast<uint4*>(&hi_lds[(ti*R*C + pix)*PITCH + cs*8]) = vh;
            *reinterpret_cast<uint4*>(&lo_lds[(ti*R*C + pix)*PITCH + cs*8]) = vl;
        }
        __syncthreads();

        bf16x8 ah[2][4], al[2][4];
        #pragma unroll
        for (int tn = 0; tn < 4; ++tn) {
            const int wo = wrow[tn] + ci0;
            ah[0][tn] = *reinterpret_cast<const bf16x8*>(&Whi[wo]);
            al[0][tn] = *reinterpret_cast<const bf16x8*>(&Wlo[wo]);
        }
        #pragma unroll
        for (int k = 0; k < 9; ++k) {
            const int cur = k & 1, nxt = cur ^ 1;
            if (k < 8) {
                #pragma unroll
                for (int tn = 0; tn < 4; ++tn) {
                    const int wo = wrow[tn] + (k+1)*CI + ci0;
                    ah[nxt][tn] = *reinterpret_cast<const bf16x8*>(&Whi[wo]);
                    al[nxt][tn] = *reinterpret_cast<const bf16x8*>(&Wlo[wo]);
                }
            }
            const int kh = k/3, kw = k%3;
            bf16x8 bh[4], bl[4];
            #pragma unroll
            for (int si = 0; si < 4; ++si) {
                const int pi = tb[si] + ((2*dyy[si]+kh)*C + 2*dxx[si]+kw)*PITCH + q*8;
                bh[si] = *reinterpret_cast<const bf16x8*>(&hi_lds[pi]);
                bl[si] = *reinterpret_cast<const bf16x8*>(&lo_lds[pi]);
            }
            #pragma unroll
            for (int si = 0; si < 4; ++si)
                #pragma unroll
                for (int tn = 0; tn < 4; ++tn) {
                    acc[si][tn] = __builtin_amdgcn_mfma_f32_16x16x32_bf16(ah[cur][tn], bh[si], acc[si][tn], 0,0,0);
                    acc[si][tn] = __builtin_amdgcn_mfma_f32_16x16x32_bf16(ah[cur][tn], bl[si], acc[si][tn], 0,0,0);
                    acc[si][tn] = __builtin_amdgcn_mfma_f32_16x16x32_bf16(al[cur][tn], bh[si], acc[si][tn], 0,0,0);
                }
        }
        __syncthreads();
    }

    #pragma unroll
    for (int si = 0; si < 4; ++si) {
        const int n_s = (NPACK==1) ? n0 : (n0 + si);
        const int oh  = (NPACK==1) ? (oh0 + dyy[si]) : dyy[si];
        const int ow  = (NPACK==1) ? (ow0 + dxx[si]) : dxx[si];
        #pragma unroll
        for (int tn = 0; tn < 4; ++tn) {
            int co_b = co0 + w*64 + tn*16 + q*4;
            ushort4 sh, sl;
            #pragma unroll
            for (int r = 0; r < 4; ++r) {
                float v = fmaxf(acc[si][tn][r] + Bias[co_b + r], 0.f);
                unsigned short h = f2bf(v);
                ((unsigned short*)&sh)[r] = h;
                ((unsigned short*)&sl)[r] = f2bf(v - bf2f(h));
            }
            long ob = (((long)n_s*HO + oh)*HO + ow)*CO + co_b;
            *reinterpret_cast<ushort4*>(&out_hi[ob]) = sh;
            *reinterpret_cast<ushort4*>(&out_lo[ob]) = sl;
        }
    }
}

// ===================== conv5: 8-way ci-split partial + reduce ==============
// GEMM M=512(co) x N=1024(n,px) x K=4608. Grid (SK=8, 4 co, 16 n-groups).
__global__ __launch_bounds__(128, 2)
void conv5_partial(const unsigned short* __restrict__ in_hi,
                   const unsigned short* __restrict__ in_lo,
                   const unsigned short* __restrict__ Whi,
                   const unsigned short* __restrict__ Wlo,
                   float* __restrict__ skbuf)
{
    constexpr int CI = 512, HI = 8;
    constexpr int R = 9, C = 9, CK = 32, PITCH = 40;
    constexpr int SK = 8, CIB = CI/SK;   // 64 ci per block

    __shared__ __align__(16) unsigned short hi_lds[4*R*C*PITCH];
    __shared__ __align__(16) unsigned short lo_lds[4*R*C*PITCH];

    const int sk  = blockIdx.x;
    const int co0 = blockIdx.y * 128;
    const int n0  = blockIdx.z * 4;
    const int t = threadIdx.x;
    const int w = t >> 6, lane = t & 63;
    const int s = lane & 15, q = lane >> 4;
    const int dyy = s >> 2, dxx = s & 3;

    int wrow[4];
    #pragma unroll
    for (int tn = 0; tn < 4; ++tn)
        wrow[tn] = (co0 + w*64 + tn*16 + s)*9*CI + q*8;

    f32x4 acc[4][4];
    #pragma unroll
    for (int si = 0; si < 4; ++si)
        #pragma unroll
        for (int tn = 0; tn < 4; ++tn)
            acc[si][tn] = (f32x4){0.f,0.f,0.f,0.f};

    for (int cc = 0; cc < CIB; cc += CK) {
        const int ci0 = sk*CIB + cc;
        constexpr int C8 = CK/8;         // 4
        constexpr int PXW = R*C*C8;      // 324
        for (int i8 = t; i8 < 4*PXW; i8 += 128) {
            int ti = i8 / PXW, rem = i8 % PXW;
            int pix = rem / C8, cs = rem % C8;
            int r = pix / C, c = pix % C;
            uint4 vh = {0u,0u,0u,0u}, vl = {0u,0u,0u,0u};
            if (r < HI && c < HI) {
                long off = (((long)(n0+ti)*HI + r)*HI + c)*CI + ci0 + cs*8;
                vh = *reinterpret_cast<const uint4*>(&in_hi[off]);
                vl = *reinterpret_cast<const uint4*>(&in_lo[off]);
            }
            *reinterpret_cast<uint4*>(&hi_lds[(ti*R*C + pix)*PITCH + cs*8]) = vh;
            *reinterpret_cast<uint4*>(&lo_lds[(ti*R*C + pix)*PITCH + cs*8]) = vl;
        }
        __syncthreads();

        bf16x8 ah[2][4], al[2][4];
        #pragma unroll
        for (int tn = 0; tn < 4; ++tn) {
            const int wo = wrow[tn] + ci0;
            ah[0][tn] = *reinterpret_cast<const bf16x8*>(&Whi[wo]);
            al[0][tn] = *reinterpret_cast<const bf16x8*>(&Wlo[wo]);
        }
        #pragma unroll
        for (int k = 0; k < 9; ++k) {
            const int cur = k & 1, nxt = cur ^ 1;
            if (k < 8) {
                #pragma unroll
                for (int tn = 0; tn < 4; ++tn) {
                    const int wo = wrow[tn] + (k+1)*CI + ci0;
                    ah[nxt][tn] = *reinterpret_cast<const bf16x8*>(&Whi[wo]);
                    al[nxt][tn] = *reinterpret_cast<const bf16x8*>(&Wlo[wo]);
                }
            }
            const int kh = k/3, kw = k%3;
            bf16x8 bh[4], bl[4];
            #pragma unroll
            for (int si = 0; si < 4; ++si) {
                const int pi = si*R*C*PITCH + ((2*dyy+kh)*C + 2*dxx+kw)*PITCH + q*8;
                bh[si] = *reinterpret_cast<const bf16x8*>(&hi_lds[pi]);
                bl[si] = *reinterpret_cast<const bf16x8*>(&lo_lds[pi]);
            }
            #pragma unroll
            for (int si = 0; si < 4; ++si)
                #pragma unroll
                for (int tn = 0; tn < 4; ++tn) {
                    acc[si][tn] = __builtin_amdgcn_mfma_f32_16x16x32_bf16(ah[cur][tn], bh[si], acc[si][tn], 0,0,0);
                    acc[si][tn] = __builtin_amdgcn_mfma_f32_16x16x32_bf16(ah[cur][tn], bl[si], acc[si][tn], 0,0,0);
                    acc[si][tn] = __builtin_amdgcn_mfma_f32_16x16x32_bf16(al[cur][tn], bh[si], acc[si][tn], 0,0,0);
                }
        }
        __syncthreads();
    }

    // partial store: skbuf[sk][n][px(=s)][co]
    #pragma unroll
    for (int si = 0; si < 4; ++si) {
        #pragma unroll
        for (int tn = 0; tn < 4; ++tn) {
            int co_b = co0 + w*64 + tn*16 + q*4;
            long o = (((long)sk*64 + n0+si)*16 + s)*512 + co_b;
            *reinterpret_cast<f32x4*>(&skbuf[o]) = acc[si][tn];
        }
    }
}

__global__ __launch_bounds__(256)
void conv5_reduce(const float* __restrict__ skbuf, const float* __restrict__ Bias,
                  unsigned short* __restrict__ fhi, unsigned short* __restrict__ flo)
{
    int i = blockIdx.x*256 + threadIdx.x;       // < 64*16*512
    int co = i & 511;
    float sacc = Bias[co];
    #pragma unroll
    for (int sk = 0; sk < 8; ++sk) sacc += skbuf[sk*524288 + i];
    float v = fmaxf(sacc, 0.f);
    unsigned short h = f2bf(v);
    fhi[i] = h;
    flo[i] = f2bf(v - bf2f(h));
}

// ===================== dec1: 4-way ci-split partial + reduce ===============
// Fused up2+conv3x3, per-sample expert weights. Grid (SK=4, 2 co, 64 n).
__global__ __launch_bounds__(128, 2)
void dec1_partial(const unsigned short* __restrict__ in,   // [64][4][4][512] bf16
                  const unsigned short* __restrict__ WT,   // [5][256][9][512] bf16
                  const int* __restrict__ cls_i,
                  float* __restrict__ dbuf)
{
    constexpr int CI = 512, CO = 256, HI = 4;
    constexpr int R = 6, C = 6, CK = 64, CKQ = 2, PITCH = 72;
    constexpr int SK = 4, CIB = CI/SK;   // 128

    __shared__ __align__(16) unsigned short ilds[R*C*PITCH];

    const int sk  = blockIdx.x;
    const int co0 = blockIdx.y * 128;
    const int n   = blockIdx.z;
    const int e   = cls_i[n];
    const int t = threadIdx.x;
    const int w = t >> 6, lane = t & 63;
    const int s = lane & 15, q = lane >> 4;

    const unsigned short* Wbase = WT + (long)e*CO*9*CI;
    const unsigned short* inN   = in + (long)n*HI*HI*CI;

    int dyy[4], dxx[4];
    #pragma unroll
    for (int si = 0; si < 4; ++si) { dyy[si] = si*2 + (s>>3); dxx[si] = s & 7; }

    long wrow[4];
    #pragma unroll
    for (int tn = 0; tn < 4; ++tn)
        wrow[tn] = (long)(co0 + w*64 + tn*16 + s)*9*CI + q*8;

    f32x4 acc[4][4];
    #pragma unroll
    for (int si = 0; si < 4; ++si)
        #pragma unroll
        for (int tn = 0; tn < 4; ++tn)
            acc[si][tn] = (f32x4){0.f,0.f,0.f,0.f};

    for (int cc = 0; cc < CIB; cc += CK) {
        const int ci0 = sk*CIB + cc;
        constexpr int C8 = CK/8;            // 8
        for (int i8 = t; i8 < R*C*C8; i8 += 128) {
            int pix = i8 / C8, cs = i8 % C8;
            int r = pix / C, c = pix % C;
            int ih = r - 1, iw = c - 1;
            uint4 v = {0u,0u,0u,0u};
            if (ih >= 0 && ih < HI && iw >= 0 && iw < HI)
                v = *reinterpret_cast<const uint4*>(&inN[((long)ih*HI + iw)*CI + ci0 + cs*8]);
            *reinterpret_cast<uint4*>(&ilds[pix*PITCH + cs*8]) = v;
        }
        __syncthreads();

        bf16x8 a[2][4];
        #pragma unroll
        for (int tn = 0; tn < 4; ++tn)
            a[0][tn] = *reinterpret_cast<const bf16x8*>(&Wbase[wrow[tn] + ci0]);
        #pragma unroll
        for (int st = 0; st < 9*CKQ; ++st) {
            const int cur = st & 1, nxt = cur ^ 1;
            if (st + 1 < 9*CKQ) {
                const int kp = (st+1)/CKQ, cp = (st+1)%CKQ;
                #pragma unroll
                for (int tn = 0; tn < 4; ++tn)
                    a[nxt][tn] = *reinterpret_cast<const bf16x8*>(
                        &Wbase[wrow[tn] + kp*CI + ci0 + cp*32]);
            }
            const int k = st/CKQ, ckq = st%CKQ;
            const int kh = k/3, kw = k%3;
            #pragma unroll
            for (int si = 0; si < 4; ++si) {
                const int ihr = ((dyy[si] + kh - 1) >> 1) + 1;
                const int iwr = ((dxx[si] + kw - 1) >> 1) + 1;
                bf16x8 b = *reinterpret_cast<const bf16x8*>(
                    &ilds[(ihr*C + iwr)*PITCH + ckq*32 + q*8]);
                #pragma unroll
                for (int tn = 0; tn < 4; ++tn)
                    acc[si][tn] = __builtin_amdgcn_mfma_f32_16x16x32_bf16(
                        a[cur][tn], b, acc[si][tn], 0, 0, 0);
            }
        }
        __syncthreads();
    }

    // partial store: dbuf[sk][n][px][co]
    #pragma unroll
    for (int si = 0; si < 4; ++si) {
        int px = dyy[si]*8 + dxx[si];
        #pragma unroll
        for (int tn = 0; tn < 4; ++tn) {
            int co_b = co0 + w*64 + tn*16 + q*4;
            long o = (((long)sk*64 + n)*64 + px)*256 + co_b;
            *reinterpret_cast<f32x4*>(&dbuf[o]) = acc[si][tn];
        }
    }
}

__global__ __launch_bounds__(256)
void dec1_reduce(const float* __restrict__ dbuf, const float* __restrict__ be1,
                 const int* __restrict__ cls_i, unsigned short* __restrict__ P)
{
    int i = blockIdx.x*256 + threadIdx.x;   // < 64*64*256
    int n = i >> 14;
    int co = i & 255;
    int e = cls_i[n];
    float sacc = be1[e*256 + co];
    #pragma unroll
    for (int sk = 0; sk < 4; ++sk) sacc += dbuf[sk*1048576 + i];
    P[i] = f2bf(fmaxf(sacc, 0.f));
}

// ===================== weight transforms ===================================
template<int CI>
__global__ __launch_bounds__(256)
void wtrans_split_kernel(const float* __restrict__ src,
                         unsigned short* __restrict__ hi,
                         unsigned short* __restrict__ lo)
{
    __shared__ float buf[CI*9];
    const long blk = blockIdx.x;
    const float* sp = src + blk*(CI*9);
    for (int i = threadIdx.x; i < CI*9; i += 256) buf[i] = sp[i];
    __syncthreads();
    for (int i = threadIdx.x; i < CI*9; i += 256) {
        int k = i / CI, ci = i % CI;
        float v = buf[ci*9 + k];
        unsigned short h = f2bf(v);
        hi[blk*(CI*9) + i] = h;
        lo[blk*(CI*9) + i] = f2bf(v - bf2f(h));
    }
}

template<int CI>
__global__ __launch_bounds__(256)
void wtrans_kernel(const float* __restrict__ src, unsigned short* __restrict__ dst)
{
    __shared__ float buf[CI*9];
    const long blk = blockIdx.x;
    const float* sp = src + blk*(CI*9);
    for (int i = threadIdx.x; i < CI*9; i += 256) buf[i] = sp[i];
    __syncthreads();
    unsigned short* d = dst + blk*(CI*9);
    for (int i = threadIdx.x; i < CI*9; i += 256) {
        int k = i / CI, ci = i % CI;
        d[i] = f2bf(buf[ci*9 + k]);
    }
}

// ===================== classifier path =====================================
__global__ __launch_bounds__(256) void pool_kernel(const unsigned short* __restrict__ fh,
                                                   const unsigned short* __restrict__ fl,
                                                   float* __restrict__ pooled)
{
    int i = blockIdx.x*256 + threadIdx.x;
    if (i < 64*512) {
        int n = i >> 9, ci = i & 511;
        const unsigned short* ph = fh + (long)n*8192 + ci;
        const unsigned short* pl = fl + (long)n*8192 + ci;
        float sacc = 0.f;
        #pragma unroll
        for (int px = 0; px < 16; ++px)
            sacc += bf2f(ph[px*512]) + bf2f(pl[px*512]);
        pooled[i] = sacc * (1.f/16.f);
    }
}

__global__ __launch_bounds__(256) void fc1_kernel(const float* __restrict__ pooled,
                                                  const float* __restrict__ Wc1,
                                                  const float* __restrict__ bc1,
                                                  float* __restrict__ hidden)
{
    int i = blockIdx.x*256 + threadIdx.x;
    if (i < 64*128) {
        int n = i/128, j = i%128;
        const float* p = pooled + n*512;
        const float* w = Wc1 + j*512;
        float sacc = 0.f;
        for (int k = 0; k < 512; ++k) sacc += p[k]*w[k];
        hidden[i] = fmaxf(sacc + bc1[j], 0.f);
    }
}

__global__ __launch_bounds__(64) void fc2_kernel(const float* __restrict__ hidden,
                                                 const float* __restrict__ Wc2,
                                                 const float* __restrict__ bc2,
                                                 float* __restrict__ out,
                                                 int* __restrict__ cls_i)
{
    int n = blockIdx.x;
    int j = threadIdx.x;
    __shared__ float lg[5];
    if (j < 5) {
        const float* h = hidden + n*128;
        const float* w = Wc2 + j*128;
        float sacc = 0.f;
        for (int k = 0; k < 128; ++k) sacc += h[k]*w[k];
        sacc += bc2[j];
        out[n*5 + j] = sacc;
        lg[j] = sacc;
    }
    __syncthreads();
    if (j == 0) {
        int am = 0; float best = lg[0];
        #pragma unroll
        for (int k = 1; k < 5; ++k) if (lg[k] > best) { best = lg[k]; am = k; }
        out[320 + n] = (float)am;
        cls_i[n] = am;
    }
}

// ===================== bf16 MFMA decoder conv v2 (dec2/3) ==================
template<int CI,int CO,int HO,int NW>
__global__ __launch_bounds__(NW*64, 2)
void dec_conv_v2(const unsigned short* __restrict__ in,
                 const unsigned short* __restrict__ WT,
                 const float* __restrict__ Be,
                 const int* __restrict__ cls_i,
                 unsigned short* __restrict__ out)
{
    constexpr int HI = HO/2;
    constexpr int R = 6, C = 6;
    constexpr int CK = 64, CKQ = CK/32;
    constexpr int PITCH = CK + 8;
    constexpr int CO_T = NW*64;
    constexpr int NTHR = NW*64;

    __shared__ __align__(16) unsigned short ilds[R*C*PITCH];

    const int n = blockIdx.z;
    const int e = cls_i[n];
    const int co0 = blockIdx.y * CO_T;
    constexpr int TILES_X = HO/8;
    const int ty = blockIdx.x / TILES_X, tx = blockIdx.x % TILES_X;
    const int oh0 = ty*8, ow0 = tx*8;
    const int ih0 = oh0/2 - 1, iw0 = ow0/2 - 1;

    const int t = threadIdx.x;
    const int w = t >> 6, lane = t & 63;
    const int s = lane & 15, q = lane >> 4;

    const unsigned short* Wbase = WT + (long)e*CO*9*CI;
    const unsigned short* inN   = in + (long)n*HI*HI*CI;

    int dyy[4], dxx[4];
    #pragma unroll
    for (int si = 0; si < 4; ++si) { dyy[si] = si*2 + (s>>3); dxx[si] = s & 7; }

    long wrow[4];
    #pragma unroll
    for (int tn = 0; tn < 4; ++tn)
        wrow[tn] = (long)(co0 + w*64 + tn*16 + s)*9*CI + q*8;

    f32x4 acc[4][4];
    #pragma unroll
    for (int si = 0; si < 4; ++si)
        #pragma unroll
        for (int tn = 0; tn < 4; ++tn)
            acc[si][tn] = (f32x4){0.f,0.f,0.f,0.f};

    for (int ci0 = 0; ci0 < CI; ci0 += CK) {
        constexpr int C8 = CK/8;
        for (int i8 = t; i8 < R*C*C8; i8 += NTHR) {
            int pix = i8 / C8, cs = i8 % C8;
            int r = pix / C, c = pix % C;
            int ih = ih0 + r, iw = iw0 + c;
            uint4 v = {0u,0u,0u,0u};
            if (ih >= 0 && ih < HI && iw >= 0 && iw < HI)
                v = *reinterpret_cast<const uint4*>(&inN[((long)ih*HI + iw)*CI + ci0 + cs*8]);
            *reinterpret_cast<uint4*>(&ilds[pix*PITCH + cs*8]) = v;
        }
        __syncthreads();

        bf16x8 a[2][4];
        #pragma unroll
        for (int tn = 0; tn < 4; ++tn)
            a[0][tn] = *reinterpret_cast<const bf16x8*>(&Wbase[wrow[tn] + ci0]);
        #pragma unroll
        for (int st = 0; st < 9*CKQ; ++st) {
            const int cur = st & 1, nxt = cur ^ 1;
            if (st + 1 < 9*CKQ) {
                const int kp = (st+1)/CKQ, cp = (st+1)%CKQ;
                #pragma unroll
                for (int tn = 0; tn < 4; ++tn)
                    a[nxt][tn] = *reinterpret_cast<const bf16x8*>(
                        &Wbase[wrow[tn] + kp*CI + ci0 + cp*32]);
            }
            const int k = st/CKQ, ckq = st%CKQ;
            const int kh = k/3, kw = k%3;
            #pragma unroll
            for (int si = 0; si < 4; ++si) {
                const int ihr = ((dyy[si] + kh - 1) >> 1) + 1;
                const int iwr = ((dxx[si] + kw - 1) >> 1) + 1;
                bf16x8 b = *reinterpret_cast<const bf16x8*>(
                    &ilds[(ihr*C + iwr)*PITCH + ckq*32 + q*8]);
                #pragma unroll
                for (int tn = 0; tn < 4; ++tn)
                    acc[si][tn] = __builtin_amdgcn_mfma_f32_16x16x32_bf16(
                        a[cur][tn], b, acc[si][tn], 0, 0, 0);
            }
        }
        __syncthreads();
    }

    #pragma unroll
    for (int si = 0; si < 4; ++si) {
        int oh = oh0 + dyy[si], ow = ow0 + dxx[si];
        #pragma unroll
        for (int tn = 0; tn < 4; ++tn) {
            int co_b = co0 + w*64 + tn*16 + q*4;
            ushort4 st4;
            #pragma unroll
            for (int r = 0; r < 4; ++r) {
                float v = acc[si][tn][r] + Be[e*CO + co_b + r];
                v = fmaxf(v, 0.f);
                ((unsigned short*)&st4)[r] = f2bf(v);
            }
            *reinterpret_cast<ushort4*>(&out[(((long)n*HO + oh)*HO + ow)*CO + co_b]) = st4;
        }
    }
}

// ===================== bf16 MFMA decoder conv (dec4/5) =====================
template<int CI,int CO,int HO,int TH,int TW,int CO_T,int CK>
__global__ __launch_bounds__(256, 2)
void dec_conv_kernel(const unsigned short* __restrict__ in,
                     const unsigned short* __restrict__ WT,
                     const float* __restrict__ Be,
                     const int* __restrict__ cls_i,
                     unsigned short* __restrict__ out)
{
    constexpr int HI = HO/2;
    constexpr int R = TH/2 + 2, C = TW/2 + 2;
    constexpr int PITCH = CK + 8;
    constexpr int NT = CO_T/16;
    constexpr int S  = (TH*TW)/64;
    constexpr int SXT = TW/8;
    constexpr int CKQ = CK/32;
    constexpr int NST = 9*CKQ;
    constexpr int PF  = 3;

    __shared__ __align__(16) unsigned short ilds[R*C*PITCH];

    const int n = blockIdx.z;
    const int e = cls_i[n];
    const int co0 = blockIdx.y * CO_T;
    constexpr int TILES_X = HO/TW;
    const int ty = blockIdx.x / TILES_X, tx = blockIdx.x % TILES_X;
    const int oh0 = ty*TH, ow0 = tx*TW;
    const int ih0 = oh0/2 - 1, iw0 = ow0/2 - 1;

    const int t = threadIdx.x;
    const int w = t >> 6;
    const int lane = t & 63;
    const int s = lane & 15;
    const int q = lane >> 4;

    const unsigned short* Wbase = WT + ((long)e*CO + co0)*9*CI;
    const unsigned short* inN   = in + (long)n*HI*HI*CI;

    int wrow[NT];
    #pragma unroll
    for (int tn = 0; tn < NT; ++tn)
        wrow[tn] = (tn*16 + s)*9*CI + q*8;

    f32x4 acc[S][NT];
    #pragma unroll
    for (int si = 0; si < S; ++si)
        #pragma unroll
        for (int tn = 0; tn < NT; ++tn)
            acc[si][tn] = (f32x4){0.f,0.f,0.f,0.f};

    int dy[S], dx[S];
    #pragma unroll
    for (int si = 0; si < S; ++si) {
        int sub = w + si*4;
        int sy = sub / SXT, sx = sub % SXT;
        dy[si] = sy*2 + (s >> 3);
        dx[si] = sx*8 + (s & 7);
    }

    for (int ci0 = 0; ci0 < CI; ci0 += CK) {
        constexpr int C8 = CK/8;
        for (int i8 = t; i8 < R*C*C8; i8 += 256) {
            int pix = i8 / C8, cs = i8 % C8;
            int r = pix / C, c = pix % C;
            int ih = ih0 + r, iw = iw0 + c;
            uint4 v = {0u,0u,0u,0u};
            if (ih >= 0 && ih < HI && iw >= 0 && iw < HI)
                v = *reinterpret_cast<const uint4*>(&inN[((long)ih*HI + iw)*CI + ci0 + cs*8]);
            *reinterpret_cast<uint4*>(&ilds[pix*PITCH + cs*8]) = v;
        }
        __syncthreads();

        bf16x8 a[NST][NT];
        #pragma unroll
        for (int pf = 0; pf < PF && pf < NST; ++pf)
            #pragma unroll
            for (int tn = 0; tn < NT; ++tn) {
                const int k = pf/CKQ, ckq = pf%CKQ;
                a[pf][tn] = *reinterpret_cast<const bf16x8*>(
                    &Wbase[wrow[tn] + k*CI + ci0 + ckq*32]);
            }
        #pragma unroll
        for (int st = 0; st < NST; ++st) {
            if (st + PF < NST) {
                const int kp = (st+PF)/CKQ, cp = (st+PF)%CKQ;
                #pragma unroll
                for (int tn = 0; tn < NT; ++tn)
                    a[st+PF][tn] = *reinterpret_cast<const bf16x8*>(
                        &Wbase[wrow[tn] + kp*CI + ci0 + cp*32]);
            }
            const int k = st/CKQ, ckq = st%CKQ;
            const int kh = k/3, kw = k%3;
            #pragma unroll
            for (int si = 0; si < S; ++si) {
                int ihr = ((dy[si] + kh - 1) >> 1) + 1;
                int iwr = ((dx[si] + kw - 1) >> 1) + 1;
                bf16x8 b = *reinterpret_cast<const bf16x8*>(
                    &ilds[(ihr*C + iwr)*PITCH + ckq*32 + q*8]);
                #pragma unroll
                for (int tn = 0; tn < NT; ++tn)
                    acc[si][tn] = __builtin_amdgcn_mfma_f32_16x16x32_bf16(
                        a[st][tn], b, acc[si][tn], 0, 0, 0);
            }
        }
        __syncthreads();
    }

    #pragma unroll
    for (int si = 0; si < S; ++si) {
        int oh = oh0 + dy[si], ow = ow0 + dx[si];
        #pragma unroll
        for (int tn = 0; tn < NT; ++tn) {
            int co_b = co0 + tn*16 + q*4;
            ushort4 st4;
            #pragma unroll
            for (int r = 0; r < 4; ++r) {
                float v = acc[si][tn][r] + Be[e*CO + co_b + r];
                v = fmaxf(v, 0.f);
                ((unsigned short*)&st4)[r] = f2bf(v);
            }
            *reinterpret_cast<ushort4*>(&out[(((long)n*HO + oh)*HO + ow)*CO + co_b]) = st4;
        }
    }
}

// ===================== 1x1 head: NHWC bf16 -> NCHW fp32 ====================
__global__ __launch_bounds__(256) void head_kernel(const unsigned short* __restrict__ d5,
                                                   const float* __restrict__ Wh,
                                                   const float* __restrict__ bh,
                                                   const int* __restrict__ cls_i,
                                                   float* __restrict__ seg)
{
    int n = blockIdx.y;
    int p = blockIdx.x*256 + threadIdx.x;
    __shared__ float w[85];
    int e = cls_i[n];
    if (threadIdx.x < 80) w[threadIdx.x] = Wh[(long)e*80 + threadIdx.x];
    if (threadIdx.x < 5)  w[80+threadIdx.x] = bh[e*5 + threadIdx.x];
    __syncthreads();
    const unsigned short* dp = d5 + ((long)n*16384 + p)*16;
    uint4 u0 = *reinterpret_cast<const uint4*>(dp);
    uint4 u1 = *reinterpret_cast<const uint4*>(dp + 8);
    float x[16];
    unsigned int uu[4] = {u0.x, u0.y, u0.z, u0.w};
    unsigned int vv[4] = {u1.x, u1.y, u1.z, u1.w};
    #pragma unroll
    for (int i = 0; i < 4; ++i) {
        x[2*i+0] = __uint_as_float(uu[i] << 16);
        x[2*i+1] = __uint_as_float(uu[i] & 0xffff0000u);
        x[8+2*i+0] = __uint_as_float(vv[i] << 16);
        x[8+2*i+1] = __uint_as_float(vv[i] & 0xffff0000u);
    }
    #pragma unroll
    for (int co = 0; co < 5; ++co) {
        float sacc = w[80+co];
        #pragma unroll
        for (int ci = 0; ci < 16; ++ci) sacc += x[ci]*w[co*16+ci];
        seg[((long)n*5 + co)*16384 + p] = sacc;
    }
}

// ===========================================================================
extern "C" void kernel_launch(void* const* d_in, const int* in_sizes, int n_in,
                              void* d_out, int out_size, void* d_ws, size_t ws_size,
                              hipStream_t stream)
{
    const float* x   = (const float*)d_in[0];
    const float* Wb1 = (const float*)d_in[1];  const float* bb1 = (const float*)d_in[2];
    const float* Wb2 = (const float*)d_in[3];  const float* bb2 = (const float*)d_in[4];
    const float* Wb3 = (const float*)d_in[5];  const float* bb3 = (const float*)d_in[6];
    const float* Wb4 = (const float*)d_in[7];  const float* bb4 = (const float*)d_in[8];
    const float* Wb5 = (const float*)d_in[9];  const float* bb5 = (const float*)d_in[10];
    const float* Wc1 = (const float*)d_in[11]; const float* bc1 = (const float*)d_in[12];
    const float* Wc2 = (const float*)d_in[13]; const float* bc2 = (const float*)d_in[14];
    const float* We1 = (const float*)d_in[15]; const float* be1 = (const float*)d_in[16];
    const float* We2 = (const float*)d_in[17]; const float* be2 = (const float*)d_in[18];
    const float* We3 = (const float*)d_in[19]; const float* be3 = (const float*)d_in[20];
    const float* We4 = (const float*)d_in[21]; const float* be4 = (const float*)d_in[22];
    const float* We5 = (const float*)d_in[23]; const float* be5 = (const float*)d_in[24];
    const float* We6 = (const float*)d_in[25]; const float* be6 = (const float*)d_in[26];

    float* out = (float*)d_out;
    char* ws = (char*)d_ws;

    // ---- X region (67 MB): H1 -> {H3, WB4/5} -> SKBUF5 -> {P, Q/DBUF1, WT1-5}
    unsigned short* H1hi = (unsigned short*)(ws + 0);
    unsigned short* H1lo = (unsigned short*)(ws + 33554432);
    unsigned short* H3hi = (unsigned short*)(ws + 0);
    unsigned short* H3lo = (unsigned short*)(ws + 8388608);
    unsigned short* WB4hi = (unsigned short*)(ws + 16777216);
    unsigned short* WB4lo = (unsigned short*)(ws + 19136512);
    unsigned short* WB5hi = (unsigned short*)(ws + 21495808);
    unsigned short* WB5lo = (unsigned short*)(ws + 26214400);
    float*          SKBUF5 = (float*)(ws + 0);              // 16,777,216 B (8 sk)
    unsigned short* P    = (unsigned short*)(ws + 0);
    unsigned short* Q    = (unsigned short*)(ws + 33554432);
    float*          DBUF1 = (float*)(ws + 33554432);        // 16,777,216 B (4 sk)
    unsigned short* WT1  = (unsigned short*)(ws + 50331648);
    unsigned short* WT2  = (unsigned short*)(ws + 62128128);
    unsigned short* WT3  = (unsigned short*)(ws + 65077248);
    unsigned short* WT4  = (unsigned short*)(ws + 65814528);
    unsigned short* WT5  = (unsigned short*)(ws + 65998848);

    // ---- Y region (33.5 MB): H2 -> {H4, FEATS, pooled/hidden/cls} ----
    char* Y = ws + 67108864;
    unsigned short* H2hi = (unsigned short*)(Y + 0);
    unsigned short* H2lo = (unsigned short*)(Y + 16777216);
    unsigned short* H4hi = (unsigned short*)(Y + 0);
    unsigned short* H4lo = (unsigned short*)(Y + 4194304);
    unsigned short* FShi = (unsigned short*)(Y + 8388608);
    unsigned short* FSlo = (unsigned short*)(Y + 9437184);
    float* pooled = (float*)(Y + 10485760);
    float* hidden = (float*)(Y + 10616832);
    int*   cls_i  = (int*)(Y + 10649600);

    // ---- W23 tail (1.5 MB) ----
    char* W23 = ws + 100663296;
    unsigned short* WB2hi = (unsigned short*)(W23 + 0);
    unsigned short* WB2lo = (unsigned short*)(W23 + 147456);
    unsigned short* WB3hi = (unsigned short*)(W23 + 294912);
    unsigned short* WB3lo = (unsigned short*)(W23 + 884736);

    // ---- backbone weight transposes (conv2/3 only; 4/5 after conv2) ----
    hipLaunchKernelGGL((wtrans_split_kernel<64>),  dim3(128), dim3(256), 0, stream, Wb2, WB2hi, WB2lo);
    hipLaunchKernelGGL((wtrans_split_kernel<128>), dim3(256), dim3(256), 0, stream, Wb3, WB3hi, WB3lo);

    // ---- conv1 (fp32 direct, split output) ----
    hipLaunchKernelGGL(conv1_kernel, dim3(64,2,64), dim3(256), 0, stream, x, Wb1, bb1, H1hi, H1lo);

    // ---- conv2 ----
    hipLaunchKernelGGL((bb_conv_v2<64,128,32,2,1>), dim3(16,1,64), dim3(128), 0, stream,
                       H1hi, H1lo, WB2hi, WB2lo, bb2, H2hi, H2lo);

    // ---- H1 dead: transpose conv4/5 + decoder weights into X ----
    hipLaunchKernelGGL((wtrans_split_kernel<256>), dim3(512), dim3(256), 0, stream, Wb4, WB4hi, WB4lo);
    hipLaunchKernelGGL((wtrans_split_kernel<512>), dim3(512), dim3(256), 0, stream, Wb5, WB5hi, WB5lo);
    hipLaunchKernelGGL((wtrans_kernel<512>), dim3(5*256), dim3(256), 0, stream, We1, WT1);
    hipLaunchKernelGGL((wtrans_kernel<256>), dim3(5*128), dim3(256), 0, stream, We2, WT2);
    hipLaunchKernelGGL((wtrans_kernel<128>), dim3(5*64),  dim3(256), 0, stream, We3, WT3);
    hipLaunchKernelGGL((wtrans_kernel<64>),  dim3(5*32),  dim3(256), 0, stream, We4, WT4);
    hipLaunchKernelGGL((wtrans_kernel<32>),  dim3(5*16),  dim3(256), 0, stream, We5, WT5);

    // ---- conv3/conv4 ----
    hipLaunchKernelGGL((bb_conv_v2<128,256,16,2,1>), dim3(4,2,64), dim3(128), 0, stream,
                       H2hi, H2lo, WB3hi, WB3lo, bb3, H3hi, H3lo);
    hipLaunchKernelGGL((bb_conv_v2<256,512, 8,2,1>), dim3(1,4,64), dim3(128), 0, stream,
                       H3hi, H3lo, WB4hi, WB4lo, bb4, H4hi, H4lo);

    // ---- conv5: split-K partials (H3 region dead -> SKBUF5) + reduce ----
    hipLaunchKernelGGL(conv5_partial, dim3(8,4,16), dim3(128), 0, stream,
                       H4hi, H4lo, WB5hi, WB5lo, SKBUF5);
    hipLaunchKernelGGL(conv5_reduce, dim3(2048), dim3(256), 0, stream,
                       SKBUF5, bb5, FShi, FSlo);

    // ---- classifier ----
    hipLaunchKernelGGL(pool_kernel, dim3(128), dim3(256), 0, stream, FShi, FSlo, pooled);
    hipLaunchKernelGGL(fc1_kernel,  dim3(32),  dim3(256), 0, stream, pooled, Wc1, bc1, hidden);
    hipLaunchKernelGGL(fc2_kernel,  dim3(64),  dim3(64),  0, stream, hidden, Wc2, bc2, out, cls_i);

    // ---- dec1: split-K partials (Q region free -> DBUF1) + reduce -> P ----
    hipLaunchKernelGGL(dec1_partial, dim3(4,2,64), dim3(128), 0, stream,
                       FShi, WT1, cls_i, DBUF1);
    hipLaunchKernelGGL(dec1_reduce, dim3(4096), dim3(256), 0, stream,
                       DBUF1, be1, cls_i, P);

    // ---- dec2..5: P -> Q -> P -> Q -> P ----
    hipLaunchKernelGGL((dec_conv_v2<256,128, 16,2>), dim3(4, 1,64), dim3(128), 0, stream, P, WT2, be2, cls_i, Q);
    hipLaunchKernelGGL((dec_conv_v2<128, 64, 32,1>), dim3(16,1,64), dim3(64),  0, stream, Q, WT3, be3, cls_i, P);
    hipLaunchKernelGGL((dec_conv_kernel< 64, 32, 64, 16,16, 32,64>), dim3(16, 1,64), dim3(256), 0, stream, P, WT4, be4, cls_i, Q);
    hipLaunchKernelGGL((dec_conv_kernel< 32, 16,128, 16,16, 16,32>), dim3(64, 1,64), dim3(256), 0, stream, Q, WT5, be5, cls_i, P);

    // ---- 1x1 head -> seg (NCHW fp32) ----
    hipLaunchKernelGGL(head_kernel, dim3(64,64), dim3(256), 0, stream, P, We6, be6, cls_i, out + 384);
}